// Round 6
// baseline (355.673 us; speedup 1.0000x reference)
//
#include <hip/hip_runtime.h>
#include <math.h>

#define CDIM 8192
#define DDIM 512
#define NEGF -3.0e38f
#define POSF  3.0e38f

#define BM 128
#define BK 64
#define NSLOT (CDIM / BM) /* 64 j-block slots per row */

typedef __attribute__((ext_vector_type(8))) short bf16x8;
typedef __attribute__((ext_vector_type(4))) float f32x4;

__device__ __forceinline__ unsigned short f2bf(float x) {
    unsigned int u = __float_as_uint(x);
    u += 0x7fffu + ((u >> 16) & 1u);
    return (unsigned short)(u >> 16);
}
__device__ __forceinline__ float bf2f(unsigned short h) {
    return __uint_as_float(((unsigned int)h) << 16);
}
// async global->LDS, 16B per lane. LDS dest is wave-uniform base + lane*16.
__device__ __forceinline__ void gld16(const void* g, void* l) {
    __builtin_amdgcn_global_load_lds(
        (__attribute__((address_space(1))) void*)(void*)g,
        (__attribute__((address_space(3))) void*)l, 16, 0, 0);
}

// ---- k_prep: normalize rows of G, split into bf16 hi/lo ----
__global__ __launch_bounds__(256) void k_prep(const float* __restrict__ g,
                                              unsigned short* __restrict__ hi,
                                              unsigned short* __restrict__ lo) {
    const int wave = threadIdx.x >> 6;
    const int lane = threadIdx.x & 63;
    const int row = blockIdx.x * 4 + wave;
    const float4* src = (const float4*)(g + (size_t)row * DDIM);
    const float4 a = src[lane * 2];
    const float4 b = src[lane * 2 + 1];
    float s = a.x * a.x + a.y * a.y + a.z * a.z + a.w * a.w +
              b.x * b.x + b.y * b.y + b.z * b.z + b.w * b.w;
#pragma unroll
    for (int m = 1; m < 64; m <<= 1) s += __shfl_xor(s, m, 64);
    const float rn = rsqrtf(s);
    const float y[8] = {a.x * rn, a.y * rn, a.z * rn, a.w * rn,
                        b.x * rn, b.y * rn, b.z * rn, b.w * rn};
    unsigned int hv[4], lv[4];
#pragma unroll
    for (int i = 0; i < 4; ++i) {
        const unsigned short h0 = f2bf(y[2 * i]);
        const unsigned short h1 = f2bf(y[2 * i + 1]);
        const unsigned short l0 = f2bf(y[2 * i] - bf2f(h0));
        const unsigned short l1 = f2bf(y[2 * i + 1] - bf2f(h1));
        hv[i] = (unsigned int)h0 | ((unsigned int)h1 << 16);
        lv[i] = (unsigned int)l0 | ((unsigned int)l1 << 16);
    }
    uint4* dh = (uint4*)(hi + (size_t)row * DDIM + lane * 8);
    uint4* dl = (uint4*)(lo + (size_t)row * DDIM + lane * 8);
    *dh = make_uint4(hv[0], hv[1], hv[2], hv[3]);
    *dl = make_uint4(lv[0], lv[1], lv[2], lv[3]);
}

// ---- k_simstats: symmetric-aware MFMA S-tiles + row/col softmax stats ----
// grid (64,64), early-exit lower triangle (J<I): 2080 live tiles.
// 128x128 tile, 4 waves as 2x2: wave (wr,wc) owns rows wr*64..+64 x cols
// wc*64..+64 as 4x4 16x16x32 frags. 3 passes hi*hi + hi*lo + lo*hi.
// Strictly-upper tiles also emit COLUMN stats (== row stats for rows J over
// cols I, by S=S^T). Partial slot layout: row i, slot p = stats over cols
// [p*128,(p+1)*128). Row-write -> slot J; col-write -> slot I. One writer
// per (row,slot).
__global__ __launch_bounds__(256, 3) void k_simstats(
    const unsigned short* __restrict__ ghi, const unsigned short* __restrict__ glo,
    float* __restrict__ pmax, float* __restrict__ pmin, float* __restrict__ pZ,
    int* __restrict__ pamax, int* __restrict__ pamin) {
    const int I = blockIdx.x, J = blockIdx.y;
    if (J < I) return;
    __shared__ unsigned short As[BM * BK];  // 16 KB
    __shared__ unsigned short Bs[BM * BK];  // 16 KB
    const int t = threadIdx.x;
    const int wave = t >> 6;
    const int lane = t & 63;
    const int lanelo = lane & 15;
    const int quad = lane >> 4;
    const int wr = wave & 1;
    const int wc = wave >> 1;
    const int i0 = I * BM;
    const int j0 = J * BM;

    // staging: thread t covers byte t*16 + q*4096 -> row (t>>3)+q*32, slot t&7
    const int srow = t >> 3;
    const int scolb = ((t & 7) ^ ((t >> 3) & 7)) << 4;  // swizzled source chunk
    char* lA = (char*)As + t * 16;
    char* lB = (char*)Bs + t * 16;

    const unsigned short* pa_tab[3] = {ghi, ghi, glo};
    const unsigned short* pb_tab[3] = {ghi, glo, ghi};

    f32x4 acc[4][4];
#pragma unroll
    for (int rt = 0; rt < 4; ++rt)
#pragma unroll
        for (int ct = 0; ct < 4; ++ct)
            acc[rt][ct] = (f32x4){0.f, 0.f, 0.f, 0.f};

    const int arow0 = (wr * 64 + lanelo) * BK;   // + rt*16*BK
    const int brow0 = (wc * 64 + lanelo) * BK;   // + ct*16*BK
    const int l7 = lanelo & 7;

    for (int p = 0; p < 3; ++p) {
        const char* baseA = (const char*)pa_tab[p] +
                            (size_t)(i0 + srow) * (DDIM * 2) + scolb;
        const char* baseB = (const char*)pb_tab[p] +
                            (size_t)(j0 + srow) * (DDIM * 2) + scolb;
        for (int k0 = 0; k0 < DDIM; k0 += BK) {
            __syncthreads();  // previous iter's frag reads done
#pragma unroll
            for (int q = 0; q < 4; ++q)
                gld16(baseA + (size_t)q * 32 * (DDIM * 2) + k0 * 2, lA + q * 4096);
#pragma unroll
            for (int q = 0; q < 4; ++q)
                gld16(baseB + (size_t)q * 32 * (DDIM * 2) + k0 * 2, lB + q * 4096);
            __syncthreads();  // drains vmcnt: staged data visible
#pragma unroll
            for (int ks = 0; ks < 2; ++ks) {
                const int sl8 = ((((ks << 2) + quad) ^ l7) << 3);
                bf16x8 af[4];
#pragma unroll
                for (int rt = 0; rt < 4; ++rt)
                    af[rt] = *(const bf16x8*)&As[arow0 + rt * 16 * BK + sl8];
#pragma unroll
                for (int ct = 0; ct < 4; ++ct) {
                    const bf16x8 bfr = *(const bf16x8*)&Bs[brow0 + ct * 16 * BK + sl8];
#pragma unroll
                    for (int rt = 0; rt < 4; ++rt)
                        acc[rt][ct] = __builtin_amdgcn_mfma_f32_16x16x32_bf16(
                            af[rt], bfr, acc[rt][ct], 0, 0, 0);
                }
            }
        }
    }

    // ---- epilogue: LDS merge buffers overlay As/Bs ----
    // C/D layout: col = lanelo, row = quad*4 + reg  [m89]
    float* rm  = (float*)As;          // row stats [2 wc][128]
    float* rz  = rm + 256;
    float* rmn = rz + 256;
    int*   ra  = (int*)(rmn + 256);
    int*   ran = ra + 256;            // 5 KB
    float* cm  = (float*)Bs;          // col stats [2 wr][128]
    float* cz  = cm + 256;
    float* cmn = cz + 256;
    int*   ca  = (int*)(cmn + 256);
    int*   can = ca + 256;            // 5 KB

    __syncthreads();  // all waves done with frag reads before LDS reuse

    const bool isdiag = (I == J);

    // ---- row stats: per wave, rows wr*64.., cols wc*64.. ----
#pragma unroll
    for (int rt = 0; rt < 4; ++rt) {
#pragma unroll
        for (int r = 0; r < 4; ++r) {
            const int lrow = wr * 64 + rt * 16 + quad * 4 + r;
            const int gi = i0 + lrow;
            float tmax = NEGF; int targ = 0x7fffffff;
            float tmin = POSF; int targn = 0x7fffffff;
            float vv[4];
#pragma unroll
            for (int ct = 0; ct < 4; ++ct) {
                const int gj = j0 + wc * 64 + ct * 16 + lanelo;
                const float v = acc[rt][ct][r];
                const bool dg = isdiag && (gj == gi);
                const float vM = dg ? NEGF : v;
                const float vm = dg ? POSF : v;
                vv[ct] = vM;
                if (vM > tmax) { tmax = vM; targ = gj; }   // ct asc = j asc
                if (vm < tmin) { tmin = vm; targn = gj; }
            }
            float se = 0.f;
#pragma unroll
            for (int ct = 0; ct < 4; ++ct) se += __expf(vv[ct] - tmax);
            float vmax = tmax; int imax = targ;
            float vmin = tmin; int imin = targn;
#pragma unroll
            for (int msk = 1; msk < 16; msk <<= 1) {
                const float v2 = __shfl_xor(vmax, msk, 64);
                const int i2 = __shfl_xor(imax, msk, 64);
                if (v2 > vmax || (v2 == vmax && i2 < imax)) { vmax = v2; imax = i2; }
                const float v3 = __shfl_xor(vmin, msk, 64);
                const int i3 = __shfl_xor(imin, msk, 64);
                if (v3 < vmin || (v3 == vmin && i3 < imin)) { vmin = v3; imin = i3; }
            }
            float zs = se * __expf(tmax - vmax);
#pragma unroll
            for (int msk = 1; msk < 16; msk <<= 1) zs += __shfl_xor(zs, msk, 64);
            if (lanelo == 0) {
                const int o = wc * 128 + lrow;
                rm[o] = vmax; rz[o] = zs; rmn[o] = vmin;
                ra[o] = imax; ran[o] = imin;
            }
        }
    }

    // ---- column stats (strictly-upper tiles only) ----
    if (!isdiag) {
#pragma unroll
        for (int ct = 0; ct < 4; ++ct) {
            const int lcol = wc * 64 + ct * 16 + lanelo;
            // in-lane over 16 row-entries (rows ascend with rt,r for fixed quad)
            float tmax = NEGF; int targ = 0x7fffffff;
            float tmin = POSF; int targn = 0x7fffffff;
#pragma unroll
            for (int rt = 0; rt < 4; ++rt)
#pragma unroll
                for (int r = 0; r < 4; ++r) {
                    const int gi = i0 + wr * 64 + rt * 16 + quad * 4 + r;
                    const float v = acc[rt][ct][r];
                    if (v > tmax) { tmax = v; targ = gi; }
                    if (v < tmin) { tmin = v; targn = gi; }
                }
            float se = 0.f;
#pragma unroll
            for (int rt = 0; rt < 4; ++rt)
#pragma unroll
                for (int r = 0; r < 4; ++r) se += __expf(acc[rt][ct][r] - tmax);
            // merge across the 4 quads (lanes sharing lanelo): masks 16,32
#pragma unroll
            for (int msk = 16; msk < 64; msk <<= 1) {
                const float m2 = __shfl_xor(tmax, msk, 64);
                const int i2 = __shfl_xor(targ, msk, 64);
                const float z2 = __shfl_xor(se, msk, 64);
                const float mn2 = __shfl_xor(tmin, msk, 64);
                const int in2 = __shfl_xor(targn, msk, 64);
                const float M = fmaxf(tmax, m2);
                se = se * __expf(tmax - M) + z2 * __expf(m2 - M);
                if (m2 > tmax || (m2 == tmax && i2 < targ)) { targ = i2; }
                tmax = M;
                if (mn2 < tmin || (mn2 == tmin && in2 < targn)) { tmin = mn2; targn = in2; }
            }
            if (quad == 0) {
                const int o = wr * 128 + lcol;
                cm[o] = tmax; cz[o] = se; cmn[o] = tmin;
                ca[o] = targ; can[o] = targn;
            }
        }
    }

    __syncthreads();

    if (t < BM) {
        // merge row-stat column-halves (wc0 cols < wc1 cols): row i0+t, slot J
        const float m0 = rm[t], m1 = rm[128 + t];
        float vmax = m0; int imax = ra[t];
        if (m1 > vmax) { vmax = m1; imax = ra[128 + t]; }
        float vmin = rmn[t]; int imin = ran[t];
        if (rmn[128 + t] < vmin) { vmin = rmn[128 + t]; imin = ran[128 + t]; }
        const float zs = rz[t] * __expf(m0 - vmax) + rz[128 + t] * __expf(m1 - vmax);
        const size_t o = (size_t)J * CDIM + i0 + t;
        pmax[o] = vmax; pmin[o] = vmin; pZ[o] = zs;
        pamax[o] = imax; pamin[o] = imin;
    } else if (!isdiag) {
        // merge col-stat row-halves (wr0 rows < wr1 rows): row j0+tt, slot I
        const int tt = t - BM;
        const float m0 = cm[tt], m1 = cm[128 + tt];
        float vmax = m0; int imax = ca[tt];
        if (m1 > vmax) { vmax = m1; imax = ca[128 + tt]; }
        float vmin = cmn[tt]; int imin = can[tt];
        if (cmn[128 + tt] < vmin) { vmin = cmn[128 + tt]; imin = can[128 + tt]; }
        const float zs = cz[tt] * __expf(m0 - vmax) + cz[128 + tt] * __expf(m1 - vmax);
        const size_t o = (size_t)I * CDIM + j0 + tt;
        pmax[o] = vmax; pmin[o] = vmin; pZ[o] = zs;
        pamax[o] = imax; pamin[o] = imin;
    }
}

// ---- k_lossc: merge 64 per-row partials -> margin/ms/ls, per-row loss ----
// one wave per row; lane p owns slot p (cols [p*128,(p+1)*128))
__global__ __launch_bounds__(256) void k_lossc(
    const float* __restrict__ pmax, const float* __restrict__ pmin,
    const float* __restrict__ pZ, const int* __restrict__ pamax,
    const int* __restrict__ pamin, const float* __restrict__ w,
    float* __restrict__ vals) {
    const int wave = threadIdx.x >> 6;
    const int lane = threadIdx.x & 63;
    const int row = blockIdx.x * 4 + wave;
    const size_t o = (size_t)lane * CDIM + row;
    const float m0 = pmax[o];
    float v = m0; int a = pamax[o];
    float u = pmin[o]; int b = pamin[o];
#pragma unroll
    for (int msk = 1; msk < 64; msk <<= 1) {
        const float v2 = __shfl_xor(v, msk, 64);
        const int i2 = __shfl_xor(a, msk, 64);
        if (v2 > v || (v2 == v && i2 < a)) { v = v2; a = i2; }
        const float v3 = __shfl_xor(u, msk, 64);
        const int i3 = __shfl_xor(b, msk, 64);
        if (v3 < u || (v3 == u && i3 < b)) { u = v3; b = i3; }
    }
    float z = pZ[o] * __expf(m0 - v);
#pragma unroll
    for (int msk = 1; msk < 64; msk <<= 1) z += __shfl_xor(z, msk, 64);
    const float margin = (1.f - __expf(u - v)) / z;  // P[ms] - P[ls]
    const int jm = a, jl = b;

    const float4* wi = (const float4*)(w + (size_t)row * DDIM);
    const float4* wm = (const float4*)(w + (size_t)jm * DDIM);
    const float4* wl = (const float4*)(w + (size_t)jl * DDIM);
    float sm = 0.f, sl = 0.f;
#pragma unroll
    for (int h = 0; h < 2; ++h) {
        const int idx = h * 64 + lane;
        const float4 x = wi[idx];
        const float4 y = wm[idx];
        const float4 c = wl[idx];
        float d;
        d = x.x - y.x; sm = fmaf(d, d, sm);
        d = x.y - y.y; sm = fmaf(d, d, sm);
        d = x.z - y.z; sm = fmaf(d, d, sm);
        d = x.w - y.w; sm = fmaf(d, d, sm);
        d = x.x - c.x; sl = fmaf(d, d, sl);
        d = x.y - c.y; sl = fmaf(d, d, sl);
        d = x.z - c.z; sl = fmaf(d, d, sl);
        d = x.w - c.w; sl = fmaf(d, d, sl);
    }
#pragma unroll
    for (int msk = 1; msk < 64; msk <<= 1) {
        sm += __shfl_xor(sm, msk, 64);
        sl += __shfl_xor(sl, msk, 64);
    }
    if (lane == 0) {
        const float val = sqrtf(sm) - sqrtf(sl) + margin;
        vals[row] = val > 0.f ? val : 0.f;
    }
}

// ---- k_final: deterministic fixed-order mean (no atomics) ----
__global__ __launch_bounds__(256) void k_final(const float* __restrict__ vals,
                                               float* __restrict__ out) {
    __shared__ float red[256];
    float s = 0.f;
    for (int i = threadIdx.x; i < CDIM; i += 256) s += vals[i];
    red[threadIdx.x] = s;
    __syncthreads();
#pragma unroll
    for (int k = 128; k > 0; k >>= 1) {
        if (threadIdx.x < (unsigned)k) red[threadIdx.x] += red[threadIdx.x + k];
        __syncthreads();
    }
    if (threadIdx.x == 0) out[0] = red[0] * (1.0f / CDIM);
}

extern "C" void kernel_launch(void* const* d_in, const int* in_sizes, int n_in,
                              void* d_out, int out_size, void* d_ws, size_t ws_size,
                              hipStream_t stream) {
    const float* g = (const float*)d_in[0];  // gt_class_embeddings [8192,512]
    const float* w = (const float*)d_in[1];  // w [8192,512]
    float* out = (float*)d_out;

    // workspace layout (~26.5 MB)
    unsigned short* ghi = (unsigned short*)d_ws;
    unsigned short* glo = ghi + (size_t)CDIM * DDIM;
    float* p = (float*)(glo + (size_t)CDIM * DDIM);
    float* pmax = p;      p += (size_t)NSLOT * CDIM;
    float* pmin = p;      p += (size_t)NSLOT * CDIM;
    float* pZ = p;        p += (size_t)NSLOT * CDIM;
    int* pamax = (int*)p; p += (size_t)NSLOT * CDIM;
    int* pamin = (int*)p; p += (size_t)NSLOT * CDIM;
    float* vals = p;      p += CDIM;

    k_prep<<<CDIM / 4, 256, 0, stream>>>(g, ghi, glo);
    dim3 g2(CDIM / BM, CDIM / BM);
    k_simstats<<<g2, 256, 0, stream>>>(ghi, glo, pmax, pmin, pZ, pamax, pamin);
    k_lossc<<<CDIM / 4, 256, 0, stream>>>(pmax, pmin, pZ, pamax, pamin, w, vals);
    k_final<<<1, 256, 0, stream>>>(vals, out);
}

// Round 7
// 312.240 us; speedup vs baseline: 1.1391x; 1.1391x over previous
//
#include <hip/hip_runtime.h>
#include <math.h>

#define CDIM 8192
#define DDIM 512
#define NEGF -3.0e38f
#define POSF  3.0e38f

#define BM 128
#define BK 128
#define NSLOT (CDIM / BM) /* 64 col-slots of 128 per row */

typedef __attribute__((ext_vector_type(8))) short bf16x8;
typedef __attribute__((ext_vector_type(4))) float f32x4;

__device__ __forceinline__ unsigned short f2bf(float x) {
    unsigned int u = __float_as_uint(x);
    u += 0x7fffu + ((u >> 16) & 1u);
    return (unsigned short)(u >> 16);
}
__device__ __forceinline__ float bf2f(unsigned short h) {
    return __uint_as_float(((unsigned int)h) << 16);
}
// async global->LDS, 16B per lane. LDS dest is wave-uniform base + lane*16.
__device__ __forceinline__ void gld16(const void* g, void* l) {
    __builtin_amdgcn_global_load_lds(
        (__attribute__((address_space(1))) void*)(void*)g,
        (__attribute__((address_space(3))) void*)l, 16, 0, 0);
}

// ---- k_prep: normalize rows of G, split into bf16 hi/lo ----
__global__ __launch_bounds__(256) void k_prep(const float* __restrict__ g,
                                              unsigned short* __restrict__ hi,
                                              unsigned short* __restrict__ lo) {
    const int wave = threadIdx.x >> 6;
    const int lane = threadIdx.x & 63;
    const int row = blockIdx.x * 4 + wave;
    const float4* src = (const float4*)(g + (size_t)row * DDIM);
    const float4 a = src[lane * 2];
    const float4 b = src[lane * 2 + 1];
    float s = a.x * a.x + a.y * a.y + a.z * a.z + a.w * a.w +
              b.x * b.x + b.y * b.y + b.z * b.z + b.w * b.w;
#pragma unroll
    for (int m = 1; m < 64; m <<= 1) s += __shfl_xor(s, m, 64);
    const float rn = rsqrtf(s);
    const float y[8] = {a.x * rn, a.y * rn, a.z * rn, a.w * rn,
                        b.x * rn, b.y * rn, b.z * rn, b.w * rn};
    unsigned int hv[4], lv[4];
#pragma unroll
    for (int i = 0; i < 4; ++i) {
        const unsigned short h0 = f2bf(y[2 * i]);
        const unsigned short h1 = f2bf(y[2 * i + 1]);
        const unsigned short l0 = f2bf(y[2 * i] - bf2f(h0));
        const unsigned short l1 = f2bf(y[2 * i + 1] - bf2f(h1));
        hv[i] = (unsigned int)h0 | ((unsigned int)h1 << 16);
        lv[i] = (unsigned int)l0 | ((unsigned int)l1 << 16);
    }
    uint4* dh = (uint4*)(hi + (size_t)row * DDIM + lane * 8);
    uint4* dl = (uint4*)(lo + (size_t)row * DDIM + lane * 8);
    *dh = make_uint4(hv[0], hv[1], hv[2], hv[3]);
    *dl = make_uint4(lv[0], lv[1], lv[2], lv[3]);
}

// ---- k_simstats: symmetric-aware, BK=128, live-tiles-only grid ----
// 2048 blocks: b<32 -> two diagonal tiles (2b,2b),(2b+1,2b+1) [scheduled
// first so their 2x duration hides under the singles]; b>=32 -> strict-upper
// tile e=b-32 via per-I counts (63-I). 128x128 tile, 4 waves as 2x2, each
// wave rt4 x ct4 16x16x32 frags, BK=128 => 12 barrier-pairs/tile at 256
// MFMAs each (round-5 density). Strict-upper tiles emit col stats (= row
// stats of the mirrored tile, S=S^T). Slot scheme: row i, slot p covers cols
// [p*128,(p+1)*128): tile (I,J) row-stats -> slot J, col-stats -> slot I.
// Exactly one writer per (row,slot).
__global__ __launch_bounds__(256, 2) void k_simstats(
    const unsigned short* __restrict__ ghi, const unsigned short* __restrict__ glo,
    float* __restrict__ pmax, float* __restrict__ pmin, float* __restrict__ pZ,
    int* __restrict__ pamax, int* __restrict__ pamin) {
    __shared__ unsigned short As[BM * BK];  // 32 KB
    __shared__ unsigned short Bs[BM * BK];  // 32 KB
    const int t = threadIdx.x;
    const int wave = t >> 6;
    const int lane = t & 63;
    const int lanelo = lane & 15;
    const int quad = lane >> 4;
    const int wr = wave & 1;
    const int wc = wave >> 1;

    int I, J, ntiles;
    if (blockIdx.x < 32) {
        I = 2 * blockIdx.x; J = I; ntiles = 2;  // two diagonal tiles
    } else {
        int e = blockIdx.x - 32;  // 0..2015 strict-upper
        I = 0;
        while (e >= 63 - I) { e -= 63 - I; ++I; }
        J = I + 1 + e;
        ntiles = 1;
    }

    // staging: thread t -> LDS 16B slot t (+q*4096) = (row=t>>4 (+16q), sc=t&15)
    // source chunk swizzled: sc ^ (row&15) so b128 frag reads are 2-way (free)
    const int srow = t >> 4;                       // 0..15
    const int scolb = (((t & 15) ^ srow) & 15) << 4;
    char* lA = (char*)As + t * 16;
    char* lB = (char*)Bs + t * 16;

    const unsigned short* pa_tab[3] = {ghi, ghi, glo};
    const unsigned short* pb_tab[3] = {ghi, glo, ghi};

    // epilogue LDS overlays
    float* rm  = (float*)As;          // row stats [2 wc][128]
    float* rz  = rm + 256;
    float* rmn = rz + 256;
    int*   ra  = (int*)(rmn + 256);
    int*   ran = ra + 256;
    float* cm  = (float*)Bs;          // col stats [2 wr][128]
    float* cz  = cm + 256;
    float* cmn = cz + 256;
    int*   ca  = (int*)(cmn + 256);
    int*   can = ca + 256;

    for (int tl = 0; tl < ntiles; ++tl) {
        const int Ie = I + tl, Je = J + tl;
        const int i0 = Ie * BM;
        const int j0 = Je * BM;
        const bool isdiag = (Ie == Je);

        f32x4 acc[4][4];
#pragma unroll
        for (int rt = 0; rt < 4; ++rt)
#pragma unroll
            for (int ct = 0; ct < 4; ++ct)
                acc[rt][ct] = (f32x4){0.f, 0.f, 0.f, 0.f};

        for (int p = 0; p < 3; ++p) {
            const char* baseA = (const char*)pa_tab[p] +
                                (size_t)(i0 + srow) * (DDIM * 2) + scolb;
            const char* baseB = (const char*)pb_tab[p] +
                                (size_t)(j0 + srow) * (DDIM * 2) + scolb;
            for (int k0 = 0; k0 < DDIM; k0 += BK) {
                __syncthreads();  // previous frag/epilogue LDS reads done
#pragma unroll
                for (int q = 0; q < 8; ++q)
                    gld16(baseA + (size_t)q * 16 * (DDIM * 2) + k0 * 2,
                          lA + q * 4096);
#pragma unroll
                for (int q = 0; q < 8; ++q)
                    gld16(baseB + (size_t)q * 16 * (DDIM * 2) + k0 * 2,
                          lB + q * 4096);
                __syncthreads();  // drains vmcnt: staged data visible
#pragma unroll
                for (int ks = 0; ks < 4; ++ks) {
                    const int slot = ((ks * 4 + quad) ^ lanelo) & 15;
                    const int soff = slot * 8;  // ushort units
                    bf16x8 af[4];
#pragma unroll
                    for (int rt = 0; rt < 4; ++rt)
                        af[rt] = *(const bf16x8*)
                            &As[((wr * 64 + rt * 16 + lanelo) << 7) + soff];
#pragma unroll
                    for (int ct = 0; ct < 4; ++ct) {
                        const bf16x8 bfr = *(const bf16x8*)
                            &Bs[((wc * 64 + ct * 16 + lanelo) << 7) + soff];
#pragma unroll
                        for (int rt = 0; rt < 4; ++rt)
                            acc[rt][ct] = __builtin_amdgcn_mfma_f32_16x16x32_bf16(
                                af[rt], bfr, acc[rt][ct], 0, 0, 0);
                    }
                }
            }
        }

        __syncthreads();  // all frag reads done before LDS overlay

        // ---- row stats: wave (wr,wc) covers rows wr*64.. x cols wc*64.. ----
        // C/D layout: col = lanelo, row = quad*4 + reg  [m89]
#pragma unroll
        for (int rt = 0; rt < 4; ++rt) {
#pragma unroll
            for (int r = 0; r < 4; ++r) {
                const int lrow = wr * 64 + rt * 16 + quad * 4 + r;
                const int gi = i0 + lrow;
                float tmax = NEGF; int targ = 0x7fffffff;
                float tmin = POSF; int targn = 0x7fffffff;
                float vv[4];
#pragma unroll
                for (int ct = 0; ct < 4; ++ct) {
                    const int gj = j0 + wc * 64 + ct * 16 + lanelo;
                    const float v = acc[rt][ct][r];
                    const bool dg = isdiag && (gj == gi);
                    const float vM = dg ? NEGF : v;
                    const float vm = dg ? POSF : v;
                    vv[ct] = vM;
                    if (vM > tmax) { tmax = vM; targ = gj; }   // ct asc = j asc
                    if (vm < tmin) { tmin = vm; targn = gj; }
                }
                float se = 0.f;
#pragma unroll
                for (int ct = 0; ct < 4; ++ct) se += __expf(vv[ct] - tmax);
                float vmax = tmax; int imax = targ;
                float vmin = tmin; int imin = targn;
#pragma unroll
                for (int msk = 1; msk < 16; msk <<= 1) {
                    const float v2 = __shfl_xor(vmax, msk, 64);
                    const int i2 = __shfl_xor(imax, msk, 64);
                    if (v2 > vmax || (v2 == vmax && i2 < imax)) { vmax = v2; imax = i2; }
                    const float v3 = __shfl_xor(vmin, msk, 64);
                    const int i3 = __shfl_xor(imin, msk, 64);
                    if (v3 < vmin || (v3 == vmin && i3 < imin)) { vmin = v3; imin = i3; }
                }
                float zs = se * __expf(tmax - vmax);
#pragma unroll
                for (int msk = 1; msk < 16; msk <<= 1) zs += __shfl_xor(zs, msk, 64);
                if (lanelo == 0) {
                    const int o = wc * 128 + lrow;
                    rm[o] = vmax; rz[o] = zs; rmn[o] = vmin;
                    ra[o] = imax; ran[o] = imin;
                }
            }
        }

        // ---- col stats (strict-upper only): stats over 128 rows per col ----
        if (!isdiag) {
#pragma unroll
            for (int ct = 0; ct < 4; ++ct) {
                const int lcol = wc * 64 + ct * 16 + lanelo;
                float tmax = NEGF; int targ = 0x7fffffff;
                float tmin = POSF; int targn = 0x7fffffff;
#pragma unroll
                for (int rt = 0; rt < 4; ++rt)
#pragma unroll
                    for (int r = 0; r < 4; ++r) {
                        const int gi = i0 + wr * 64 + rt * 16 + quad * 4 + r;
                        const float v = acc[rt][ct][r];
                        if (v > tmax) { tmax = v; targ = gi; }  // gi asc in (rt,r)
                        if (v < tmin) { tmin = v; targn = gi; }
                    }
                float se = 0.f;
#pragma unroll
                for (int rt = 0; rt < 4; ++rt)
#pragma unroll
                    for (int r = 0; r < 4; ++r)
                        se += __expf(acc[rt][ct][r] - tmax);
                // merge across the 4 quads (masks 16,32 stay in-wave)
#pragma unroll
                for (int msk = 16; msk < 64; msk <<= 1) {
                    const float m2 = __shfl_xor(tmax, msk, 64);
                    const int i2 = __shfl_xor(targ, msk, 64);
                    const float z2 = __shfl_xor(se, msk, 64);
                    const float mn2 = __shfl_xor(tmin, msk, 64);
                    const int in2 = __shfl_xor(targn, msk, 64);
                    const float M = fmaxf(tmax, m2);
                    se = se * __expf(tmax - M) + z2 * __expf(m2 - M);
                    if (m2 > tmax || (m2 == tmax && i2 < targ)) { targ = i2; }
                    tmax = M;
                    if (mn2 < tmin || (mn2 == tmin && in2 < targn)) { tmin = mn2; targn = in2; }
                }
                if (quad == 0) {
                    const int o = wr * 128 + lcol;
                    cm[o] = tmax; cz[o] = se; cmn[o] = tmin;
                    ca[o] = targ; can[o] = targn;
                }
            }
        }

        __syncthreads();

        if (t < BM) {
            // merge row-stat wc-halves (wc0 cols < wc1): row i0+t, slot Je
            const float m0 = rm[t], m1 = rm[128 + t];
            float vmax = m0; int imax = ra[t];
            if (m1 > vmax) { vmax = m1; imax = ra[128 + t]; }
            float vmin = rmn[t]; int imin = ran[t];
            if (rmn[128 + t] < vmin) { vmin = rmn[128 + t]; imin = ran[128 + t]; }
            const float zs = rz[t] * __expf(m0 - vmax) +
                             rz[128 + t] * __expf(m1 - vmax);
            const size_t o = (size_t)Je * CDIM + i0 + t;
            pmax[o] = vmax; pmin[o] = vmin; pZ[o] = zs;
            pamax[o] = imax; pamin[o] = imin;
        } else if (!isdiag) {
            // merge col-stat wr-halves (wr0 rows < wr1): row j0+tt, slot Ie
            const int tt = t - BM;
            const float m0 = cm[tt], m1 = cm[128 + tt];
            float vmax = m0; int imax = ca[tt];
            if (m1 > vmax) { vmax = m1; imax = ca[128 + tt]; }
            float vmin = cmn[tt]; int imin = can[tt];
            if (cmn[128 + tt] < vmin) { vmin = cmn[128 + tt]; imin = can[128 + tt]; }
            const float zs = cz[tt] * __expf(m0 - vmax) +
                             cz[128 + tt] * __expf(m1 - vmax);
            const size_t o = (size_t)Ie * CDIM + j0 + tt;
            pmax[o] = vmax; pmin[o] = vmin; pZ[o] = zs;
            pamax[o] = imax; pamin[o] = imin;
        }
        // next tile's K-loop leading __syncthreads guards these LDS reads
    }
}

// ---- k_lossc: merge 64 per-row partials -> margin/ms/ls, per-row loss ----
// one wave per row; lane p owns slot p (cols [p*128,(p+1)*128))
__global__ __launch_bounds__(256) void k_lossc(
    const float* __restrict__ pmax, const float* __restrict__ pmin,
    const float* __restrict__ pZ, const int* __restrict__ pamax,
    const int* __restrict__ pamin, const float* __restrict__ w,
    float* __restrict__ vals) {
    const int wave = threadIdx.x >> 6;
    const int lane = threadIdx.x & 63;
    const int row = blockIdx.x * 4 + wave;
    const size_t o = (size_t)lane * CDIM + row;
    const float m0 = pmax[o];
    float v = m0; int a = pamax[o];
    float u = pmin[o]; int b = pamin[o];
#pragma unroll
    for (int msk = 1; msk < 64; msk <<= 1) {
        const float v2 = __shfl_xor(v, msk, 64);
        const int i2 = __shfl_xor(a, msk, 64);
        if (v2 > v || (v2 == v && i2 < a)) { v = v2; a = i2; }
        const float v3 = __shfl_xor(u, msk, 64);
        const int i3 = __shfl_xor(b, msk, 64);
        if (v3 < u || (v3 == u && i3 < b)) { u = v3; b = i3; }
    }
    float z = pZ[o] * __expf(m0 - v);
#pragma unroll
    for (int msk = 1; msk < 64; msk <<= 1) z += __shfl_xor(z, msk, 64);
    const float margin = (1.f - __expf(u - v)) / z;  // P[ms] - P[ls]
    const int jm = a, jl = b;

    const float4* wi = (const float4*)(w + (size_t)row * DDIM);
    const float4* wm = (const float4*)(w + (size_t)jm * DDIM);
    const float4* wl = (const float4*)(w + (size_t)jl * DDIM);
    float sm = 0.f, sl = 0.f;
#pragma unroll
    for (int h = 0; h < 2; ++h) {
        const int idx = h * 64 + lane;
        const float4 x = wi[idx];
        const float4 y = wm[idx];
        const float4 c = wl[idx];
        float d;
        d = x.x - y.x; sm = fmaf(d, d, sm);
        d = x.y - y.y; sm = fmaf(d, d, sm);
        d = x.z - y.z; sm = fmaf(d, d, sm);
        d = x.w - y.w; sm = fmaf(d, d, sm);
        d = x.x - c.x; sl = fmaf(d, d, sl);
        d = x.y - c.y; sl = fmaf(d, d, sl);
        d = x.z - c.z; sl = fmaf(d, d, sl);
        d = x.w - c.w; sl = fmaf(d, d, sl);
    }
#pragma unroll
    for (int msk = 1; msk < 64; msk <<= 1) {
        sm += __shfl_xor(sm, msk, 64);
        sl += __shfl_xor(sl, msk, 64);
    }
    if (lane == 0) {
        const float val = sqrtf(sm) - sqrtf(sl) + margin;
        vals[row] = val > 0.f ? val : 0.f;
    }
}

// ---- k_final: deterministic fixed-order mean (no atomics) ----
__global__ __launch_bounds__(256) void k_final(const float* __restrict__ vals,
                                               float* __restrict__ out) {
    __shared__ float red[256];
    float s = 0.f;
    for (int i = threadIdx.x; i < CDIM; i += 256) s += vals[i];
    red[threadIdx.x] = s;
    __syncthreads();
#pragma unroll
    for (int k = 128; k > 0; k >>= 1) {
        if (threadIdx.x < (unsigned)k) red[threadIdx.x] += red[threadIdx.x + k];
        __syncthreads();
    }
    if (threadIdx.x == 0) out[0] = red[0] * (1.0f / CDIM);
}

extern "C" void kernel_launch(void* const* d_in, const int* in_sizes, int n_in,
                              void* d_out, int out_size, void* d_ws, size_t ws_size,
                              hipStream_t stream) {
    const float* g = (const float*)d_in[0];  // gt_class_embeddings [8192,512]
    const float* w = (const float*)d_in[1];  // w [8192,512]
    float* out = (float*)d_out;

    // workspace layout (~26.5 MB)
    unsigned short* ghi = (unsigned short*)d_ws;
    unsigned short* glo = ghi + (size_t)CDIM * DDIM;
    float* p = (float*)(glo + (size_t)CDIM * DDIM);
    float* pmax = p;      p += (size_t)NSLOT * CDIM;
    float* pmin = p;      p += (size_t)NSLOT * CDIM;
    float* pZ = p;        p += (size_t)NSLOT * CDIM;
    int* pamax = (int*)p; p += (size_t)NSLOT * CDIM;
    int* pamin = (int*)p; p += (size_t)NSLOT * CDIM;
    float* vals = p;      p += CDIM;

    k_prep<<<CDIM / 4, 256, 0, stream>>>(g, ghi, glo);
    k_simstats<<<2048, 256, 0, stream>>>(ghi, glo, pmax, pmin, pZ, pamax, pamin);
    k_lossc<<<CDIM / 4, 256, 0, stream>>>(pmax, pmin, pZ, pamax, pamin, w, vals);
    k_final<<<1, 256, 0, stream>>>(vals, out);
}

// Round 8
// 276.568 us; speedup vs baseline: 1.2860x; 1.1290x over previous
//
#include <hip/hip_runtime.h>
#include <math.h>

#define CDIM 8192
#define DDIM 512
#define NEGF -3.0e38f
#define POSF  3.0e38f

#define BM 128
#define NSLOT (CDIM / BM) /* 64 col-slots of 128 per row */

typedef __attribute__((ext_vector_type(8))) short bf16x8;
typedef __attribute__((ext_vector_type(4))) float f32x4;

__device__ __forceinline__ unsigned short f2bf(float x) {
    unsigned int u = __float_as_uint(x);
    u += 0x7fffu + ((u >> 16) & 1u);
    return (unsigned short)(u >> 16);
}
__device__ __forceinline__ float bf2f(unsigned short h) {
    return __uint_as_float(((unsigned int)h) << 16);
}
// async global->LDS, 16B per lane. LDS dest is wave-uniform base + lane*16.
__device__ __forceinline__ void gld16(const void* g, void* l) {
    __builtin_amdgcn_global_load_lds(
        (__attribute__((address_space(1))) void*)(void*)g,
        (__attribute__((address_space(3))) void*)l, 16, 0, 0);
}

// ---- k_prep: normalize rows of G, split into bf16 hi/lo ----
__global__ __launch_bounds__(256) void k_prep(const float* __restrict__ g,
                                              unsigned short* __restrict__ hi,
                                              unsigned short* __restrict__ lo) {
    const int wave = threadIdx.x >> 6;
    const int lane = threadIdx.x & 63;
    const int row = blockIdx.x * 4 + wave;
    const float4* src = (const float4*)(g + (size_t)row * DDIM);
    const float4 a = src[lane * 2];
    const float4 b = src[lane * 2 + 1];
    float s = a.x * a.x + a.y * a.y + a.z * a.z + a.w * a.w +
              b.x * b.x + b.y * b.y + b.z * b.z + b.w * b.w;
#pragma unroll
    for (int m = 1; m < 64; m <<= 1) s += __shfl_xor(s, m, 64);
    const float rn = rsqrtf(s);
    const float y[8] = {a.x * rn, a.y * rn, a.z * rn, a.w * rn,
                        b.x * rn, b.y * rn, b.z * rn, b.w * rn};
    unsigned int hv[4], lv[4];
#pragma unroll
    for (int i = 0; i < 4; ++i) {
        const unsigned short h0 = f2bf(y[2 * i]);
        const unsigned short h1 = f2bf(y[2 * i + 1]);
        const unsigned short l0 = f2bf(y[2 * i] - bf2f(h0));
        const unsigned short l1 = f2bf(y[2 * i + 1] - bf2f(h1));
        hv[i] = (unsigned int)h0 | ((unsigned int)h1 << 16);
        lv[i] = (unsigned int)l0 | ((unsigned int)l1 << 16);
    }
    uint4* dh = (uint4*)(hi + (size_t)row * DDIM + lane * 8);
    uint4* dl = (uint4*)(lo + (size_t)row * DDIM + lane * 8);
    *dh = make_uint4(hv[0], hv[1], hv[2], hv[3]);
    *dl = make_uint4(lv[0], lv[1], lv[2], lv[3]);
}

// ---- k_simstats: symmetric-aware, XCD-local J-major tiles, hi+lo co-staged ----
// 2048 blocks. vid = (bid%8)*256 + bid/8 gives each XCD (round-robin bid%8)
// a contiguous 256-range: off<4 -> diag-pair block (2 diagonal tiles,
// dispatched first: bid<32); else strict-upper tile, J-major order (blocks
// sharing J are consecutive within an XCD -> B-tile L2-resident; A streams
// from L3-resident 16MB dataset). 128x128 tile, 4 waves 2x2, rt4 x ct4
// 16x16x32 frags. Per K-chunk (BK=64) stage Ahi/Alo/Bhi/Blo (64KB LDS) and
// run hi*hi + hi*lo + lo*hi from one staging: 8 barrier-pairs, 96 MFMA each.
// Strict-upper tiles also emit col stats (= mirrored-tile row stats, S=S^T).
// Slot scheme: row i, slot p covers cols [p*128,(p+1)*128); row-stats->slot
// J, col-stats->slot I. One writer per (row,slot).
__global__ __launch_bounds__(256, 2) void k_simstats(
    const unsigned short* __restrict__ ghi, const unsigned short* __restrict__ glo,
    float* __restrict__ pmax, float* __restrict__ pmin, float* __restrict__ pZ,
    int* __restrict__ pamax, int* __restrict__ pamin) {
    __shared__ unsigned short SH[4 * BM * 64];  // 64 KB: Ahi|Alo|Bhi|Blo
    unsigned short* Ahi = SH;
    unsigned short* Alo = SH + 8192;
    unsigned short* Bhi = SH + 16384;
    unsigned short* Blo = SH + 24576;
    const int t = threadIdx.x;
    const int wave = t >> 6;
    const int lane = t & 63;
    const int lanelo = lane & 15;
    const int quad = lane >> 4;
    const int wr = wave & 1;
    const int wc = wave >> 1;

    // ---- tile mapping ----
    const int bid = blockIdx.x;
    const int xcd = bid & 7;
    const int off = bid >> 3;
    int I, J, ntiles;
    if (off < 4) {
        const int d = xcd * 4 + off;       // 0..31
        I = 2 * d; J = I; ntiles = 2;      // two diagonal tiles
    } else {
        const int e = xcd * 252 + (off - 4);  // 0..2015, J-major
        int Jf = (int)((1.0f + sqrtf(1.0f + 8.0f * (float)e)) * 0.5f);
        while ((Jf * (Jf - 1)) / 2 > e) --Jf;
        while (((Jf + 1) * Jf) / 2 <= e) ++Jf;
        J = Jf; I = e - (Jf * (Jf - 1)) / 2;
        ntiles = 1;
    }

    // staging: thread t -> per-region LDS slot t*16 + q*4096
    //   = (row = (t>>3)+32q, chunk-slot = t&7); source chunk = slot ^ (row&7)
    const int srow = t >> 3;                             // 0..31
    const int scolb = ((t & 7) ^ ((t >> 3) & 7)) << 4;   // swizzled src chunk
    char* lAh = (char*)Ahi + t * 16;
    char* lAl = (char*)Alo + t * 16;
    char* lBh = (char*)Bhi + t * 16;
    char* lBl = (char*)Blo + t * 16;

    // epilogue LDS overlays
    float* rm  = (float*)SH;            // row stats [2 wc][128]
    float* rz  = rm + 256;
    float* rmn = rz + 256;
    int*   ra  = (int*)(rmn + 256);
    int*   ran = ra + 256;
    float* cm  = (float*)Bhi;           // col stats [2 wr][128]
    float* cz  = cm + 256;
    float* cmn = cz + 256;
    int*   ca  = (int*)(cmn + 256);
    int*   can = ca + 256;

    const int l7 = lanelo & 7;

    for (int tl = 0; tl < ntiles; ++tl) {
        const int Ie = I + tl, Je = J + tl;
        const int i0 = Ie * BM;
        const int j0 = Je * BM;
        const bool isdiag = (Ie == Je);

        f32x4 acc[4][4];
#pragma unroll
        for (int rt = 0; rt < 4; ++rt)
#pragma unroll
            for (int ct = 0; ct < 4; ++ct)
                acc[rt][ct] = (f32x4){0.f, 0.f, 0.f, 0.f};

        const char* baseAh = (const char*)ghi + (size_t)(i0 + srow) * 1024 + scolb;
        const char* baseAl = (const char*)glo + (size_t)(i0 + srow) * 1024 + scolb;
        const char* baseBh = (const char*)ghi + (size_t)(j0 + srow) * 1024 + scolb;
        const char* baseBl = (const char*)glo + (size_t)(j0 + srow) * 1024 + scolb;

        for (int k0 = 0; k0 < DDIM; k0 += 64) {
            __syncthreads();  // prior frag/epilogue LDS reads done
#pragma unroll
            for (int q = 0; q < 4; ++q) {
                const size_t roff = (size_t)q * 32 * 1024 + k0 * 2;
                gld16(baseAh + roff, lAh + q * 4096);
                gld16(baseAl + roff, lAl + q * 4096);
                gld16(baseBh + roff, lBh + q * 4096);
                gld16(baseBl + roff, lBl + q * 4096);
            }
            __syncthreads();  // drains vmcnt: staged data visible
#pragma unroll
            for (int ks = 0; ks < 2; ++ks) {
                const int sl8 = ((((ks << 2) + quad) ^ l7) << 3);
                bf16x8 ah[4], al[4];
#pragma unroll
                for (int rt = 0; rt < 4; ++rt) {
                    const int ro = ((wr * 64 + rt * 16 + lanelo) << 6) + sl8;
                    ah[rt] = *(const bf16x8*)&Ahi[ro];
                    al[rt] = *(const bf16x8*)&Alo[ro];
                }
#pragma unroll
                for (int ct = 0; ct < 4; ++ct) {
                    const int co = ((wc * 64 + ct * 16 + lanelo) << 6) + sl8;
                    const bf16x8 bh = *(const bf16x8*)&Bhi[co];
                    const bf16x8 bl = *(const bf16x8*)&Blo[co];
#pragma unroll
                    for (int rt = 0; rt < 4; ++rt) {
                        acc[rt][ct] = __builtin_amdgcn_mfma_f32_16x16x32_bf16(
                            ah[rt], bh, acc[rt][ct], 0, 0, 0);
                        acc[rt][ct] = __builtin_amdgcn_mfma_f32_16x16x32_bf16(
                            ah[rt], bl, acc[rt][ct], 0, 0, 0);
                        acc[rt][ct] = __builtin_amdgcn_mfma_f32_16x16x32_bf16(
                            al[rt], bh, acc[rt][ct], 0, 0, 0);
                    }
                }
            }
        }

        __syncthreads();  // all frag reads done before LDS overlay

        // ---- row stats: wave (wr,wc) covers rows wr*64.. x cols wc*64.. ----
        // C/D layout: col = lanelo, row = quad*4 + reg  [m89]
#pragma unroll
        for (int rt = 0; rt < 4; ++rt) {
#pragma unroll
            for (int r = 0; r < 4; ++r) {
                const int lrow = wr * 64 + rt * 16 + quad * 4 + r;
                const int gi = i0 + lrow;
                float tmax = NEGF; int targ = 0x7fffffff;
                float tmin = POSF; int targn = 0x7fffffff;
                float vv[4];
#pragma unroll
                for (int ct = 0; ct < 4; ++ct) {
                    const int gj = j0 + wc * 64 + ct * 16 + lanelo;
                    const float v = acc[rt][ct][r];
                    const bool dg = isdiag && (gj == gi);
                    const float vM = dg ? NEGF : v;
                    const float vm = dg ? POSF : v;
                    vv[ct] = vM;
                    if (vM > tmax) { tmax = vM; targ = gj; }   // ct asc = j asc
                    if (vm < tmin) { tmin = vm; targn = gj; }
                }
                float se = 0.f;
#pragma unroll
                for (int ct = 0; ct < 4; ++ct) se += __expf(vv[ct] - tmax);
                float vmax = tmax; int imax = targ;
                float vmin = tmin; int imin = targn;
#pragma unroll
                for (int msk = 1; msk < 16; msk <<= 1) {
                    const float v2 = __shfl_xor(vmax, msk, 64);
                    const int i2 = __shfl_xor(imax, msk, 64);
                    if (v2 > vmax || (v2 == vmax && i2 < imax)) { vmax = v2; imax = i2; }
                    const float v3 = __shfl_xor(vmin, msk, 64);
                    const int i3 = __shfl_xor(imin, msk, 64);
                    if (v3 < vmin || (v3 == vmin && i3 < imin)) { vmin = v3; imin = i3; }
                }
                float zs = se * __expf(tmax - vmax);
#pragma unroll
                for (int msk = 1; msk < 16; msk <<= 1) zs += __shfl_xor(zs, msk, 64);
                if (lanelo == 0) {
                    const int o = wc * 128 + lrow;
                    rm[o] = vmax; rz[o] = zs; rmn[o] = vmin;
                    ra[o] = imax; ran[o] = imin;
                }
            }
        }

        // ---- col stats (strict-upper only): stats over 128 rows per col ----
        if (!isdiag) {
#pragma unroll
            for (int ct = 0; ct < 4; ++ct) {
                const int lcol = wc * 64 + ct * 16 + lanelo;
                float tmax = NEGF; int targ = 0x7fffffff;
                float tmin = POSF; int targn = 0x7fffffff;
#pragma unroll
                for (int rt = 0; rt < 4; ++rt)
#pragma unroll
                    for (int r = 0; r < 4; ++r) {
                        const int gi = i0 + wr * 64 + rt * 16 + quad * 4 + r;
                        const float v = acc[rt][ct][r];
                        if (v > tmax) { tmax = v; targ = gi; }  // gi asc in (rt,r)
                        if (v < tmin) { tmin = v; targn = gi; }
                    }
                float se = 0.f;
#pragma unroll
                for (int rt = 0; rt < 4; ++rt)
#pragma unroll
                    for (int r = 0; r < 4; ++r)
                        se += __expf(acc[rt][ct][r] - tmax);
                // merge across the 4 quads (masks 16,32 stay in-wave)
#pragma unroll
                for (int msk = 16; msk < 64; msk <<= 1) {
                    const float m2 = __shfl_xor(tmax, msk, 64);
                    const int i2 = __shfl_xor(targ, msk, 64);
                    const float z2 = __shfl_xor(se, msk, 64);
                    const float mn2 = __shfl_xor(tmin, msk, 64);
                    const int in2 = __shfl_xor(targn, msk, 64);
                    const float M = fmaxf(tmax, m2);
                    se = se * __expf(tmax - M) + z2 * __expf(m2 - M);
                    if (m2 > tmax || (m2 == tmax && i2 < targ)) { targ = i2; }
                    tmax = M;
                    if (mn2 < tmin || (mn2 == tmin && in2 < targn)) { tmin = mn2; targn = in2; }
                }
                if (quad == 0) {
                    const int o = wr * 128 + lcol;
                    cm[o] = tmax; cz[o] = se; cmn[o] = tmin;
                    ca[o] = targ; can[o] = targn;
                }
            }
        }

        __syncthreads();

        if (t < BM) {
            // merge row-stat wc-halves (wc0 cols < wc1): row i0+t, slot Je
            const float m0 = rm[t], m1 = rm[128 + t];
            float vmax = m0; int imax = ra[t];
            if (m1 > vmax) { vmax = m1; imax = ra[128 + t]; }
            float vmin = rmn[t]; int imin = ran[t];
            if (rmn[128 + t] < vmin) { vmin = rmn[128 + t]; imin = ran[128 + t]; }
            const float zs = rz[t] * __expf(m0 - vmax) +
                             rz[128 + t] * __expf(m1 - vmax);
            const size_t o = (size_t)Je * CDIM + i0 + t;
            pmax[o] = vmax; pmin[o] = vmin; pZ[o] = zs;
            pamax[o] = imax; pamin[o] = imin;
        } else if (!isdiag) {
            // merge col-stat wr-halves (wr0 rows < wr1): row j0+tt, slot Ie
            const int tt = t - BM;
            const float m0 = cm[tt], m1 = cm[128 + tt];
            float vmax = m0; int imax = ca[tt];
            if (m1 > vmax) { vmax = m1; imax = ca[128 + tt]; }
            float vmin = cmn[tt]; int imin = can[tt];
            if (cmn[128 + tt] < vmin) { vmin = cmn[128 + tt]; imin = can[128 + tt]; }
            const float zs = cz[tt] * __expf(m0 - vmax) +
                             cz[128 + tt] * __expf(m1 - vmax);
            const size_t o = (size_t)Ie * CDIM + j0 + tt;
            pmax[o] = vmax; pmin[o] = vmin; pZ[o] = zs;
            pamax[o] = imax; pamin[o] = imin;
        }
        // next tile's K-loop leading __syncthreads guards these LDS reads
    }
}

// ---- k_lossc: merge 64 per-row partials -> margin/ms/ls, per-row loss ----
// one wave per row; lane p owns slot p (cols [p*128,(p+1)*128))
__global__ __launch_bounds__(256) void k_lossc(
    const float* __restrict__ pmax, const float* __restrict__ pmin,
    const float* __restrict__ pZ, const int* __restrict__ pamax,
    const int* __restrict__ pamin, const float* __restrict__ w,
    float* __restrict__ vals) {
    const int wave = threadIdx.x >> 6;
    const int lane = threadIdx.x & 63;
    const int row = blockIdx.x * 4 + wave;
    const size_t o = (size_t)lane * CDIM + row;
    const float m0 = pmax[o];
    float v = m0; int a = pamax[o];
    float u = pmin[o]; int b = pamin[o];
#pragma unroll
    for (int msk = 1; msk < 64; msk <<= 1) {
        const float v2 = __shfl_xor(v, msk, 64);
        const int i2 = __shfl_xor(a, msk, 64);
        if (v2 > v || (v2 == v && i2 < a)) { v = v2; a = i2; }
        const float v3 = __shfl_xor(u, msk, 64);
        const int i3 = __shfl_xor(b, msk, 64);
        if (v3 < u || (v3 == u && i3 < b)) { u = v3; b = i3; }
    }
    float z = pZ[o] * __expf(m0 - v);
#pragma unroll
    for (int msk = 1; msk < 64; msk <<= 1) z += __shfl_xor(z, msk, 64);
    const float margin = (1.f - __expf(u - v)) / z;  // P[ms] - P[ls]
    const int jm = a, jl = b;

    const float4* wi = (const float4*)(w + (size_t)row * DDIM);
    const float4* wm = (const float4*)(w + (size_t)jm * DDIM);
    const float4* wl = (const float4*)(w + (size_t)jl * DDIM);
    float sm = 0.f, sl = 0.f;
#pragma unroll
    for (int h = 0; h < 2; ++h) {
        const int idx = h * 64 + lane;
        const float4 x = wi[idx];
        const float4 y = wm[idx];
        const float4 c = wl[idx];
        float d;
        d = x.x - y.x; sm = fmaf(d, d, sm);
        d = x.y - y.y; sm = fmaf(d, d, sm);
        d = x.z - y.z; sm = fmaf(d, d, sm);
        d = x.w - y.w; sm = fmaf(d, d, sm);
        d = x.x - c.x; sl = fmaf(d, d, sl);
        d = x.y - c.y; sl = fmaf(d, d, sl);
        d = x.z - c.z; sl = fmaf(d, d, sl);
        d = x.w - c.w; sl = fmaf(d, d, sl);
    }
#pragma unroll
    for (int msk = 1; msk < 64; msk <<= 1) {
        sm += __shfl_xor(sm, msk, 64);
        sl += __shfl_xor(sl, msk, 64);
    }
    if (lane == 0) {
        const float val = sqrtf(sm) - sqrtf(sl) + margin;
        vals[row] = val > 0.f ? val : 0.f;
    }
}

// ---- k_final: deterministic fixed-order mean (no atomics) ----
__global__ __launch_bounds__(256) void k_final(const float* __restrict__ vals,
                                               float* __restrict__ out) {
    __shared__ float red[256];
    float s = 0.f;
    for (int i = threadIdx.x; i < CDIM; i += 256) s += vals[i];
    red[threadIdx.x] = s;
    __syncthreads();
#pragma unroll
    for (int k = 128; k > 0; k >>= 1) {
        if (threadIdx.x < (unsigned)k) red[threadIdx.x] += red[threadIdx.x + k];
        __syncthreads();
    }
    if (threadIdx.x == 0) out[0] = red[0] * (1.0f / CDIM);
}

extern "C" void kernel_launch(void* const* d_in, const int* in_sizes, int n_in,
                              void* d_out, int out_size, void* d_ws, size_t ws_size,
                              hipStream_t stream) {
    const float* g = (const float*)d_in[0];  // gt_class_embeddings [8192,512]
    const float* w = (const float*)d_in[1];  // w [8192,512]
    float* out = (float*)d_out;

    // workspace layout (~26.5 MB)
    unsigned short* ghi = (unsigned short*)d_ws;
    unsigned short* glo = ghi + (size_t)CDIM * DDIM;
    float* p = (float*)(glo + (size_t)CDIM * DDIM);
    float* pmax = p;      p += (size_t)NSLOT * CDIM;
    float* pmin = p;      p += (size_t)NSLOT * CDIM;
    float* pZ = p;        p += (size_t)NSLOT * CDIM;
    int* pamax = (int*)p; p += (size_t)NSLOT * CDIM;
    int* pamin = (int*)p; p += (size_t)NSLOT * CDIM;
    float* vals = p;      p += CDIM;

    k_prep<<<CDIM / 4, 256, 0, stream>>>(g, ghi, glo);
    k_simstats<<<2048, 256, 0, stream>>>(ghi, glo, pmax, pmin, pZ, pamax, pamin);
    k_lossc<<<CDIM / 4, 256, 0, stream>>>(pmax, pmin, pZ, pamax, pamin, w, vals);
    k_final<<<1, 256, 0, stream>>>(vals, out);
}

// Round 9
// 253.912 us; speedup vs baseline: 1.4008x; 1.0892x over previous
//
#include <hip/hip_runtime.h>
#include <math.h>

#define CDIM 8192
#define DDIM 512
#define NEGF -3.0e38f
#define POSF  3.0e38f

#define BM 128
#define NSLOT (CDIM / BM) /* 64 col-slots of 128 per row */

typedef __attribute__((ext_vector_type(8))) short bf16x8;
typedef __attribute__((ext_vector_type(4))) float f32x4;

__device__ __forceinline__ unsigned short f2bf(float x) {
    unsigned int u = __float_as_uint(x);
    u += 0x7fffu + ((u >> 16) & 1u);
    return (unsigned short)(u >> 16);
}
__device__ __forceinline__ float bf2f(unsigned short h) {
    return __uint_as_float(((unsigned int)h) << 16);
}
// async global->LDS, 16B per lane. LDS dest is wave-uniform base + lane*16.
__device__ __forceinline__ void gld16(const void* g, void* l) {
    __builtin_amdgcn_global_load_lds(
        (__attribute__((address_space(1))) void*)(void*)g,
        (__attribute__((address_space(3))) void*)l, 16, 0, 0);
}

// ---- k_prep: normalize rows of G, split into bf16 hi/lo ----
__global__ __launch_bounds__(256) void k_prep(const float* __restrict__ g,
                                              unsigned short* __restrict__ hi,
                                              unsigned short* __restrict__ lo) {
    const int wave = threadIdx.x >> 6;
    const int lane = threadIdx.x & 63;
    const int row = blockIdx.x * 4 + wave;
    const float4* src = (const float4*)(g + (size_t)row * DDIM);
    const float4 a = src[lane * 2];
    const float4 b = src[lane * 2 + 1];
    float s = a.x * a.x + a.y * a.y + a.z * a.z + a.w * a.w +
              b.x * b.x + b.y * b.y + b.z * b.z + b.w * b.w;
#pragma unroll
    for (int m = 1; m < 64; m <<= 1) s += __shfl_xor(s, m, 64);
    const float rn = rsqrtf(s);
    const float y[8] = {a.x * rn, a.y * rn, a.z * rn, a.w * rn,
                        b.x * rn, b.y * rn, b.z * rn, b.w * rn};
    unsigned int hv[4], lv[4];
#pragma unroll
    for (int i = 0; i < 4; ++i) {
        const unsigned short h0 = f2bf(y[2 * i]);
        const unsigned short h1 = f2bf(y[2 * i + 1]);
        const unsigned short l0 = f2bf(y[2 * i] - bf2f(h0));
        const unsigned short l1 = f2bf(y[2 * i + 1] - bf2f(h1));
        hv[i] = (unsigned int)h0 | ((unsigned int)h1 << 16);
        lv[i] = (unsigned int)l0 | ((unsigned int)l1 << 16);
    }
    uint4* dh = (uint4*)(hi + (size_t)row * DDIM + lane * 8);
    uint4* dl = (uint4*)(lo + (size_t)row * DDIM + lane * 8);
    *dh = make_uint4(hv[0], hv[1], hv[2], hv[3]);
    *dl = make_uint4(lv[0], lv[1], lv[2], lv[3]);
}

// ---- k_simstats: symmetric, XCD-local J-major, co-staged, BK=32, 32KB LDS ----
// Fixed-reference softmax: Zref = sum exp(S-1) (S in [-1,1] so exp in
// [.135,1] -- no overflow/underflow, no running max, partials add plainly).
// 2048 blocks; bid%8 = XCD, contiguous 256-range per XCD: off<4 -> two
// diagonal tiles (dispatched first), else strict-upper tile J-major (B-tile
// L2-resident across consecutive blocks). 128x128 tile, 4 waves 2x2, rt4 x
// ct4 16x16x32 frags; per K-chunk (BK=32) stage Ahi|Alo|Bhi|Blo (32 KB) and
// run hi*hi+hi*lo+lo*hi: 16 barrier-pairs/tile, 48 MFMA/wave each.
// Strict-upper tiles also emit col stats (mirror rows, S=S^T). Slot p of row
// i covers cols [p*128,(p+1)*128): row-stats->slot J, col-stats->slot I.
__global__ __launch_bounds__(256, 3) void k_simstats(
    const unsigned short* __restrict__ ghi, const unsigned short* __restrict__ glo,
    float* __restrict__ pmax, float* __restrict__ pmin, float* __restrict__ pZ,
    int* __restrict__ pamax, int* __restrict__ pamin) {
    __shared__ unsigned short SH[4 * BM * 32];  // 32 KB: Ahi|Alo|Bhi|Blo
    unsigned short* Ahi = SH;
    unsigned short* Alo = SH + 4096;
    unsigned short* Bhi = SH + 8192;
    unsigned short* Blo = SH + 12288;
    const int t = threadIdx.x;
    const int wave = t >> 6;
    const int lane = t & 63;
    const int lanelo = lane & 15;
    const int quad = lane >> 4;
    const int wr = wave & 1;
    const int wc = wave >> 1;

    // ---- tile mapping ----
    const int bid = blockIdx.x;
    const int xcd = bid & 7;
    const int off = bid >> 3;
    int I, J, ntiles;
    if (off < 4) {
        const int d = xcd * 4 + off;       // 0..31
        I = 2 * d; J = I; ntiles = 2;      // two diagonal tiles
    } else {
        const int e = xcd * 252 + (off - 4);  // 0..2015, J-major
        int Jf = (int)((1.0f + sqrtf(1.0f + 8.0f * (float)e)) * 0.5f);
        while ((Jf * (Jf - 1)) / 2 > e) --Jf;
        while (((Jf + 1) * Jf) / 2 <= e) ++Jf;
        J = Jf; I = e - (Jf * (Jf - 1)) / 2;
        ntiles = 1;
    }

    // staging: per region thread t fills slots t*16 + q*4096 ->
    // (row = (t>>2)+64q, chunk-slot = t&3); src chunk = slot ^ ((row>>1)&3)
    const int srow = t >> 2;                             // 0..63
    const int scolb = ((t & 3) ^ ((t >> 3) & 3)) << 4;   // swizzled src chunk
    char* lAh = (char*)Ahi + t * 16;
    char* lAl = (char*)Alo + t * 16;
    char* lBh = (char*)Bhi + t * 16;
    char* lBl = (char*)Blo + t * 16;

    // frag-read slot (ushort units): quad ^ ((lanelo>>1)&3), loop-invariant
    const int fsl = (quad ^ ((lanelo >> 1) & 3)) << 3;
    // row offsets within a region (ushort units): m*32
    const int aoff = (wr * 64 + lanelo) * 32 + fsl;  // + rt*16*32
    const int boff = (wc * 64 + lanelo) * 32 + fsl;  // + ct*16*32

    // epilogue LDS overlays (A half: row stats; B half: col stats)
    float* rm  = (float*)SH;            // [2 wc][128]
    float* rz  = rm + 256;
    float* rmn = rz + 256;
    int*   ra  = (int*)(rmn + 256);
    int*   ran = ra + 256;              // 5 KB < 8 KB (Ahi+Alo)
    float* cm  = (float*)Bhi;           // [2 wr][128]
    float* cz  = cm + 256;
    float* cmn = cz + 256;
    int*   ca  = (int*)(cmn + 256);
    int*   can = ca + 256;

    for (int tl = 0; tl < ntiles; ++tl) {
        const int Ie = I + tl, Je = J + tl;
        const int i0 = Ie * BM;
        const int j0 = Je * BM;
        const bool isdiag = (Ie == Je);

        f32x4 acc[4][4];
#pragma unroll
        for (int rt = 0; rt < 4; ++rt)
#pragma unroll
            for (int ct = 0; ct < 4; ++ct)
                acc[rt][ct] = (f32x4){0.f, 0.f, 0.f, 0.f};

        const char* baseAh = (const char*)ghi + (size_t)(i0 + srow) * 1024 + scolb;
        const char* baseAl = (const char*)glo + (size_t)(i0 + srow) * 1024 + scolb;
        const char* baseBh = (const char*)ghi + (size_t)(j0 + srow) * 1024 + scolb;
        const char* baseBl = (const char*)glo + (size_t)(j0 + srow) * 1024 + scolb;

        for (int k0 = 0; k0 < DDIM; k0 += 32) {
            __syncthreads();  // prior frag/epilogue LDS reads done
#pragma unroll
            for (int q = 0; q < 2; ++q) {
                const size_t roff = (size_t)q * 64 * 1024 + k0 * 2;
                gld16(baseAh + roff, lAh + q * 4096);
                gld16(baseAl + roff, lAl + q * 4096);
                gld16(baseBh + roff, lBh + q * 4096);
                gld16(baseBl + roff, lBl + q * 4096);
            }
            __syncthreads();  // drains vmcnt: staged data visible
            bf16x8 ah[4], al[4];
#pragma unroll
            for (int rt = 0; rt < 4; ++rt) {
                ah[rt] = *(const bf16x8*)&Ahi[aoff + rt * 512];
                al[rt] = *(const bf16x8*)&Alo[aoff + rt * 512];
            }
#pragma unroll
            for (int ct = 0; ct < 4; ++ct) {
                const bf16x8 bh = *(const bf16x8*)&Bhi[boff + ct * 512];
                const bf16x8 bl = *(const bf16x8*)&Blo[boff + ct * 512];
#pragma unroll
                for (int rt = 0; rt < 4; ++rt) {
                    acc[rt][ct] = __builtin_amdgcn_mfma_f32_16x16x32_bf16(
                        ah[rt], bh, acc[rt][ct], 0, 0, 0);
                    acc[rt][ct] = __builtin_amdgcn_mfma_f32_16x16x32_bf16(
                        ah[rt], bl, acc[rt][ct], 0, 0, 0);
                    acc[rt][ct] = __builtin_amdgcn_mfma_f32_16x16x32_bf16(
                        al[rt], bh, acc[rt][ct], 0, 0, 0);
                }
            }
        }

        __syncthreads();  // all frag reads done before LDS overlay

        // ---- phase 1: row max/min (original acc) ----
        // C/D layout: col = lanelo, row = quad*4 + reg  [m89]
#pragma unroll
        for (int rt = 0; rt < 4; ++rt) {
#pragma unroll
            for (int r = 0; r < 4; ++r) {
                const int lrow = wr * 64 + rt * 16 + quad * 4 + r;
                const int gi = i0 + lrow;
                float tmax = NEGF; int targ = 0x7fffffff;
                float tmin = POSF; int targn = 0x7fffffff;
#pragma unroll
                for (int ct = 0; ct < 4; ++ct) {
                    const int gj = j0 + wc * 64 + ct * 16 + lanelo;
                    const float v = acc[rt][ct][r];
                    const bool dg = isdiag && (gj == gi);
                    const float vM = dg ? NEGF : v;
                    const float vm = dg ? POSF : v;
                    if (vM > tmax) { tmax = vM; targ = gj; }   // ct asc = j asc
                    if (vm < tmin) { tmin = vm; targn = gj; }
                }
#pragma unroll
                for (int msk = 1; msk < 16; msk <<= 1) {
                    const float v2 = __shfl_xor(tmax, msk, 64);
                    const int i2 = __shfl_xor(targ, msk, 64);
                    if (v2 > tmax || (v2 == tmax && i2 < targ)) { tmax = v2; targ = i2; }
                    const float v3 = __shfl_xor(tmin, msk, 64);
                    const int i3 = __shfl_xor(targn, msk, 64);
                    if (v3 < tmin || (v3 == tmin && i3 < targn)) { tmin = v3; targn = i3; }
                }
                if (lanelo == 0) {
                    const int o = wc * 128 + lrow;
                    rm[o] = tmax; rmn[o] = tmin;
                    ra[o] = targ; ran[o] = targn;
                }
            }
        }

        // ---- phase 2: col max/min (strict-upper only, original acc) ----
        if (!isdiag) {
#pragma unroll
            for (int ct = 0; ct < 4; ++ct) {
                const int lcol = wc * 64 + ct * 16 + lanelo;
                float tmax = NEGF; int targ = 0x7fffffff;
                float tmin = POSF; int targn = 0x7fffffff;
#pragma unroll
                for (int rt = 0; rt < 4; ++rt)
#pragma unroll
                    for (int r = 0; r < 4; ++r) {
                        const int gi = i0 + wr * 64 + rt * 16 + quad * 4 + r;
                        const float v = acc[rt][ct][r];
                        if (v > tmax) { tmax = v; targ = gi; }  // gi asc in (rt,r)
                        if (v < tmin) { tmin = v; targn = gi; }
                    }
#pragma unroll
                for (int msk = 16; msk < 64; msk <<= 1) {
                    const float m2 = __shfl_xor(tmax, msk, 64);
                    const int i2 = __shfl_xor(targ, msk, 64);
                    if (m2 > tmax || (m2 == tmax && i2 < targ)) { tmax = m2; targ = i2; }
                    const float mn2 = __shfl_xor(tmin, msk, 64);
                    const int in2 = __shfl_xor(targn, msk, 64);
                    if (mn2 < tmin || (mn2 == tmin && in2 < targn)) { tmin = mn2; targn = in2; }
                }
                if (quad == 0) {
                    const int o = wr * 128 + lcol;
                    cm[o] = tmax; cmn[o] = tmin;
                    ca[o] = targ; can[o] = targn;
                }
            }
        }

        // ---- phase 3: overwrite acc with exp(S-1); diag entries -> 0 ----
#pragma unroll
        for (int rt = 0; rt < 4; ++rt)
#pragma unroll
            for (int ct = 0; ct < 4; ++ct)
#pragma unroll
                for (int r = 0; r < 4; ++r) {
                    float e = __expf(acc[rt][ct][r] - 1.f);
                    if (isdiag) {
                        const int gi = i0 + wr * 64 + rt * 16 + quad * 4 + r;
                        const int gj = j0 + wc * 64 + ct * 16 + lanelo;
                        if (gi == gj) e = 0.f;
                    }
                    acc[rt][ct][r] = e;
                }

        // ---- phase 4: row Zref sums ----
#pragma unroll
        for (int rt = 0; rt < 4; ++rt)
#pragma unroll
            for (int r = 0; r < 4; ++r) {
                float s = acc[rt][0][r] + acc[rt][1][r] +
                          acc[rt][2][r] + acc[rt][3][r];
#pragma unroll
                for (int msk = 1; msk < 16; msk <<= 1) s += __shfl_xor(s, msk, 64);
                if (lanelo == 0)
                    rz[wc * 128 + wr * 64 + rt * 16 + quad * 4 + r] = s;
            }

        // ---- phase 5: col Zref sums (strict-upper only) ----
        if (!isdiag) {
#pragma unroll
            for (int ct = 0; ct < 4; ++ct) {
                float s = 0.f;
#pragma unroll
                for (int rt = 0; rt < 4; ++rt)
                    s += acc[rt][ct][0] + acc[rt][ct][1] +
                         acc[rt][ct][2] + acc[rt][ct][3];
#pragma unroll
                for (int msk = 16; msk < 64; msk <<= 1) s += __shfl_xor(s, msk, 64);
                if (quad == 0)
                    cz[wr * 128 + wc * 64 + ct * 16 + lanelo] = s;
            }
        }

        __syncthreads();

        if (t < BM) {
            // merge row-stat wc-halves (wc0 cols < wc1): row i0+t, slot Je
            const float m0 = rm[t], m1 = rm[128 + t];
            float vmax = m0; int imax = ra[t];
            if (m1 > vmax) { vmax = m1; imax = ra[128 + t]; }
            float vmin = rmn[t]; int imin = ran[t];
            if (rmn[128 + t] < vmin) { vmin = rmn[128 + t]; imin = ran[128 + t]; }
            const size_t o = (size_t)Je * CDIM + i0 + t;
            pmax[o] = vmax; pmin[o] = vmin; pZ[o] = rz[t] + rz[128 + t];
            pamax[o] = imax; pamin[o] = imin;
        } else if (!isdiag) {
            // merge col-stat wr-halves (wr0 rows < wr1): row j0+tt, slot Ie
            const int tt = t - BM;
            const float m0 = cm[tt], m1 = cm[128 + tt];
            float vmax = m0; int imax = ca[tt];
            if (m1 > vmax) { vmax = m1; imax = ca[128 + tt]; }
            float vmin = cmn[tt]; int imin = can[tt];
            if (cmn[128 + tt] < vmin) { vmin = cmn[128 + tt]; imin = can[128 + tt]; }
            const size_t o = (size_t)Ie * CDIM + j0 + tt;
            pmax[o] = vmax; pmin[o] = vmin; pZ[o] = cz[tt] + cz[128 + tt];
            pamax[o] = imax; pamin[o] = imin;
        }
        // next tile's K-loop leading __syncthreads guards these LDS reads
    }
}

// ---- k_lossc: merge 64 per-row partials -> margin/ms/ls, per-row loss ----
// one wave per row; lane p owns slot p (cols [p*128,(p+1)*128))
__global__ __launch_bounds__(256) void k_lossc(
    const float* __restrict__ pmax, const float* __restrict__ pmin,
    const float* __restrict__ pZ, const int* __restrict__ pamax,
    const int* __restrict__ pamin, const float* __restrict__ w,
    float* __restrict__ vals) {
    const int wave = threadIdx.x >> 6;
    const int lane = threadIdx.x & 63;
    const int row = blockIdx.x * 4 + wave;
    const size_t o = (size_t)lane * CDIM + row;
    float v = pmax[o]; int a = pamax[o];
    float u = pmin[o]; int b = pamin[o];
    float z = pZ[o];
#pragma unroll
    for (int msk = 1; msk < 64; msk <<= 1) {
        const float v2 = __shfl_xor(v, msk, 64);
        const int i2 = __shfl_xor(a, msk, 64);
        if (v2 > v || (v2 == v && i2 < a)) { v = v2; a = i2; }
        const float v3 = __shfl_xor(u, msk, 64);
        const int i3 = __shfl_xor(b, msk, 64);
        if (v3 < u || (v3 == u && i3 < b)) { u = v3; b = i3; }
        z += __shfl_xor(z, msk, 64);
    }
    // P[ms]-P[ls] = (1 - exp(mn-M)) * exp(M-1) / Zref
    const float margin = (1.f - __expf(u - v)) * __expf(v - 1.f) / z;
    const int jm = a, jl = b;

    const float4* wi = (const float4*)(w + (size_t)row * DDIM);
    const float4* wm = (const float4*)(w + (size_t)jm * DDIM);
    const float4* wl = (const float4*)(w + (size_t)jl * DDIM);
    float sm = 0.f, sl = 0.f;
#pragma unroll
    for (int h = 0; h < 2; ++h) {
        const int idx = h * 64 + lane;
        const float4 x = wi[idx];
        const float4 y = wm[idx];
        const float4 c = wl[idx];
        float d;
        d = x.x - y.x; sm = fmaf(d, d, sm);
        d = x.y - y.y; sm = fmaf(d, d, sm);
        d = x.z - y.z; sm = fmaf(d, d, sm);
        d = x.w - y.w; sm = fmaf(d, d, sm);
        d = x.x - c.x; sl = fmaf(d, d, sl);
        d = x.y - c.y; sl = fmaf(d, d, sl);
        d = x.z - c.z; sl = fmaf(d, d, sl);
        d = x.w - c.w; sl = fmaf(d, d, sl);
    }
#pragma unroll
    for (int msk = 1; msk < 64; msk <<= 1) {
        sm += __shfl_xor(sm, msk, 64);
        sl += __shfl_xor(sl, msk, 64);
    }
    if (lane == 0) {
        const float val = sqrtf(sm) - sqrtf(sl) + margin;
        vals[row] = val > 0.f ? val : 0.f;
    }
}

// ---- k_final: deterministic fixed-order mean (no atomics) ----
__global__ __launch_bounds__(256) void k_final(const float* __restrict__ vals,
                                               float* __restrict__ out) {
    __shared__ float red[256];
    float s = 0.f;
    for (int i = threadIdx.x; i < CDIM; i += 256) s += vals[i];
    red[threadIdx.x] = s;
    __syncthreads();
#pragma unroll
    for (int k = 128; k > 0; k >>= 1) {
        if (threadIdx.x < (unsigned)k) red[threadIdx.x] += red[threadIdx.x + k];
        __syncthreads();
    }
    if (threadIdx.x == 0) out[0] = red[0] * (1.0f / CDIM);
}

extern "C" void kernel_launch(void* const* d_in, const int* in_sizes, int n_in,
                              void* d_out, int out_size, void* d_ws, size_t ws_size,
                              hipStream_t stream) {
    const float* g = (const float*)d_in[0];  // gt_class_embeddings [8192,512]
    const float* w = (const float*)d_in[1];  // w [8192,512]
    float* out = (float*)d_out;

    // workspace layout (~26.5 MB)
    unsigned short* ghi = (unsigned short*)d_ws;
    unsigned short* glo = ghi + (size_t)CDIM * DDIM;
    float* p = (float*)(glo + (size_t)CDIM * DDIM);
    float* pmax = p;      p += (size_t)NSLOT * CDIM;
    float* pmin = p;      p += (size_t)NSLOT * CDIM;
    float* pZ = p;        p += (size_t)NSLOT * CDIM;
    int* pamax = (int*)p; p += (size_t)NSLOT * CDIM;
    int* pamin = (int*)p; p += (size_t)NSLOT * CDIM;
    float* vals = p;      p += CDIM;

    k_prep<<<CDIM / 4, 256, 0, stream>>>(g, ghi, glo);
    k_simstats<<<2048, 256, 0, stream>>>(ghi, glo, pmax, pmin, pZ, pamax, pamin);
    k_lossc<<<CDIM / 4, 256, 0, stream>>>(pmax, pmin, pZ, pamax, pamin, w, vals);
    k_final<<<1, 256, 0, stream>>>(vals, out);
}

// Round 10
// 249.827 us; speedup vs baseline: 1.4237x; 1.0164x over previous
//
#include <hip/hip_runtime.h>
#include <math.h>

#define CDIM 8192
#define DDIM 512
#define NEGF -3.0e38f
#define POSF  3.0e38f

#define BM 128
#define NSLOT (CDIM / BM) /* 64 col-slots of 128 per row */

typedef __attribute__((ext_vector_type(8))) short bf16x8;
typedef __attribute__((ext_vector_type(4))) float f32x4;

__device__ __forceinline__ unsigned short f2bf(float x) {
    unsigned int u = __float_as_uint(x);
    u += 0x7fffu + ((u >> 16) & 1u);
    return (unsigned short)(u >> 16);
}
__device__ __forceinline__ float bf2f(unsigned short h) {
    return __uint_as_float(((unsigned int)h) << 16);
}
// async global->LDS, 16B per lane. LDS dest is wave-uniform base + lane*16.
__device__ __forceinline__ void gld16(const void* g, void* l) {
    __builtin_amdgcn_global_load_lds(
        (__attribute__((address_space(1))) void*)(void*)g,
        (__attribute__((address_space(3))) void*)l, 16, 0, 0);
}

// ---- k_prep: normalize rows of G, split into bf16 hi/lo ----
__global__ __launch_bounds__(256) void k_prep(const float* __restrict__ g,
                                              unsigned short* __restrict__ hi,
                                              unsigned short* __restrict__ lo) {
    const int wave = threadIdx.x >> 6;
    const int lane = threadIdx.x & 63;
    const int row = blockIdx.x * 4 + wave;
    const float4* src = (const float4*)(g + (size_t)row * DDIM);
    const float4 a = src[lane * 2];
    const float4 b = src[lane * 2 + 1];
    float s = a.x * a.x + a.y * a.y + a.z * a.z + a.w * a.w +
              b.x * b.x + b.y * b.y + b.z * b.z + b.w * b.w;
#pragma unroll
    for (int m = 1; m < 64; m <<= 1) s += __shfl_xor(s, m, 64);
    const float rn = rsqrtf(s);
    const float y[8] = {a.x * rn, a.y * rn, a.z * rn, a.w * rn,
                        b.x * rn, b.y * rn, b.z * rn, b.w * rn};
    unsigned int hv[4], lv[4];
#pragma unroll
    for (int i = 0; i < 4; ++i) {
        const unsigned short h0 = f2bf(y[2 * i]);
        const unsigned short h1 = f2bf(y[2 * i + 1]);
        const unsigned short l0 = f2bf(y[2 * i] - bf2f(h0));
        const unsigned short l1 = f2bf(y[2 * i + 1] - bf2f(h1));
        hv[i] = (unsigned int)h0 | ((unsigned int)h1 << 16);
        lv[i] = (unsigned int)l0 | ((unsigned int)l1 << 16);
    }
    uint4* dh = (uint4*)(hi + (size_t)row * DDIM + lane * 8);
    uint4* dl = (uint4*)(lo + (size_t)row * DDIM + lane * 8);
    *dh = make_uint4(hv[0], hv[1], hv[2], hv[3]);
    *dl = make_uint4(lv[0], lv[1], lv[2], lv[3]);
}

// ---- k_simstats: symmetric, XCD-local J-major, co-staged, BK=32, 32KB LDS ----
// Fixed-reference softmax: Zref = sum exp(S-1) (S in [-1,1] -> exp in
// [.135,1]: no overflow/underflow, no running max, partials add plainly).
// 2048 blocks; bid%8 = XCD, contiguous 256-range per XCD: off<4 -> two
// diagonal tiles (dispatched first), else strict-upper tile J-major (B-tile
// L2-resident across consecutive blocks). 128x128 tile, 4 waves 2x2, rt4 x
// ct4 16x16x32 frags; per K-chunk (BK=32) stage Ahi|Alo|Bhi|Blo (32 KB) and
// run hi*hi+hi*lo+lo*hi: 16 barrier-pairs/tile, 48 MFMA/wave each.
// Strict-upper tiles also emit col stats (mirror rows, S=S^T). Slot p of row
// i covers cols [p*128,(p+1)*128): row-stats->slot J, col-stats->slot I.
// NOTE: cross-lane merges use strict >/< without index tie-break (exact fp32
// value ties across lanes: measure-zero; within-lane scan order preserves
// numpy first-occurrence).
__global__ __launch_bounds__(256, 3) void k_simstats(
    const unsigned short* __restrict__ ghi, const unsigned short* __restrict__ glo,
    float* __restrict__ pmax, float* __restrict__ pmin, float* __restrict__ pZ,
    int* __restrict__ pamax, int* __restrict__ pamin) {
    __shared__ unsigned short SH[4 * BM * 32];  // 32 KB: Ahi|Alo|Bhi|Blo
    unsigned short* Ahi = SH;
    unsigned short* Alo = SH + 4096;
    unsigned short* Bhi = SH + 8192;
    unsigned short* Blo = SH + 12288;
    const int t = threadIdx.x;
    const int wave = t >> 6;
    const int lane = t & 63;
    const int lanelo = lane & 15;
    const int quad = lane >> 4;
    const int wr = wave & 1;
    const int wc = wave >> 1;

    // ---- tile mapping ----
    const int bid = blockIdx.x;
    const int xcd = bid & 7;
    const int off = bid >> 3;
    int I, J, ntiles;
    if (off < 4) {
        const int d = xcd * 4 + off;       // 0..31
        I = 2 * d; J = I; ntiles = 2;      // two diagonal tiles
    } else {
        const int e = xcd * 252 + (off - 4);  // 0..2015, J-major
        int Jf = (int)((1.0f + sqrtf(1.0f + 8.0f * (float)e)) * 0.5f);
        while ((Jf * (Jf - 1)) / 2 > e) --Jf;
        while (((Jf + 1) * Jf) / 2 <= e) ++Jf;
        J = Jf; I = e - (Jf * (Jf - 1)) / 2;
        ntiles = 1;
    }

    // staging: per region thread t fills slots t*16 + q*4096 ->
    // (row = (t>>2)+64q, chunk-slot = t&3); src chunk = slot ^ ((row>>1)&3)
    const int srow = t >> 2;                             // 0..63
    const int scolb = ((t & 3) ^ ((t >> 3) & 3)) << 4;   // swizzled src chunk
    char* lAh = (char*)Ahi + t * 16;
    char* lAl = (char*)Alo + t * 16;
    char* lBh = (char*)Bhi + t * 16;
    char* lBl = (char*)Blo + t * 16;

    // frag-read slot (ushort units): quad ^ ((lanelo>>1)&3), loop-invariant
    const int fsl = (quad ^ ((lanelo >> 1) & 3)) << 3;
    const int aoff = (wr * 64 + lanelo) * 32 + fsl;  // + rt*16*32
    const int boff = (wc * 64 + lanelo) * 32 + fsl;  // + ct*16*32

    // epilogue LDS overlays (A half: row stats; B half: col stats)
    float* rm  = (float*)SH;            // [2 wc][128]
    float* rz  = rm + 256;
    float* rmn = rz + 256;
    int*   ra  = (int*)(rmn + 256);
    int*   ran = ra + 256;              // 5 KB < 8 KB (Ahi+Alo)
    float* cm  = (float*)Bhi;           // [2 wr][128]
    float* cz  = cm + 256;
    float* cmn = cz + 256;
    int*   ca  = (int*)(cmn + 256);
    int*   can = ca + 256;

    for (int tl = 0; tl < ntiles; ++tl) {
        const int Ie = I + tl, Je = J + tl;
        const int i0 = Ie * BM;
        const int j0 = Je * BM;
        const bool isdiag = (Ie == Je);

        f32x4 acc[4][4];
#pragma unroll
        for (int rt = 0; rt < 4; ++rt)
#pragma unroll
            for (int ct = 0; ct < 4; ++ct)
                acc[rt][ct] = (f32x4){0.f, 0.f, 0.f, 0.f};

        const char* baseAh = (const char*)ghi + (size_t)(i0 + srow) * 1024 + scolb;
        const char* baseAl = (const char*)glo + (size_t)(i0 + srow) * 1024 + scolb;
        const char* baseBh = (const char*)ghi + (size_t)(j0 + srow) * 1024 + scolb;
        const char* baseBl = (const char*)glo + (size_t)(j0 + srow) * 1024 + scolb;

        for (int k0 = 0; k0 < DDIM; k0 += 32) {
            __syncthreads();  // prior frag/epilogue LDS reads done
#pragma unroll
            for (int q = 0; q < 2; ++q) {
                const size_t roff = (size_t)q * 64 * 1024 + k0 * 2;
                gld16(baseAh + roff, lAh + q * 4096);
                gld16(baseAl + roff, lAl + q * 4096);
                gld16(baseBh + roff, lBh + q * 4096);
                gld16(baseBl + roff, lBl + q * 4096);
            }
            __syncthreads();  // drains vmcnt: staged data visible
            bf16x8 ah[4], al[4];
#pragma unroll
            for (int rt = 0; rt < 4; ++rt) {
                ah[rt] = *(const bf16x8*)&Ahi[aoff + rt * 512];
                al[rt] = *(const bf16x8*)&Alo[aoff + rt * 512];
            }
#pragma unroll
            for (int ct = 0; ct < 4; ++ct) {
                const bf16x8 bh = *(const bf16x8*)&Bhi[boff + ct * 512];
                const bf16x8 bl = *(const bf16x8*)&Blo[boff + ct * 512];
#pragma unroll
                for (int rt = 0; rt < 4; ++rt) {
                    acc[rt][ct] = __builtin_amdgcn_mfma_f32_16x16x32_bf16(
                        ah[rt], bh, acc[rt][ct], 0, 0, 0);
                    acc[rt][ct] = __builtin_amdgcn_mfma_f32_16x16x32_bf16(
                        ah[rt], bl, acc[rt][ct], 0, 0, 0);
                    acc[rt][ct] = __builtin_amdgcn_mfma_f32_16x16x32_bf16(
                        al[rt], bh, acc[rt][ct], 0, 0, 0);
                }
            }
        }

        __syncthreads();  // all frag reads done before LDS overlay

        // ---- phase 1: row max/min (original acc) ----
        // C/D layout: col = lanelo, row = quad*4 + reg  [m89]
#pragma unroll
        for (int rt = 0; rt < 4; ++rt) {
#pragma unroll
            for (int r = 0; r < 4; ++r) {
                const int lrow = wr * 64 + rt * 16 + quad * 4 + r;
                float tmax = NEGF; int targ = 0;
                float tmin = POSF; int targn = 0;
                if (isdiag) {
                    const int gi = i0 + lrow;
#pragma unroll
                    for (int ct = 0; ct < 4; ++ct) {
                        const int gj = j0 + wc * 64 + ct * 16 + lanelo;
                        const float v = acc[rt][ct][r];
                        const bool dg = (gj == gi);
                        const float vM = dg ? NEGF : v;
                        const float vm = dg ? POSF : v;
                        if (vM > tmax) { tmax = vM; targ = gj; }  // ct asc = j asc
                        if (vm < tmin) { tmin = vm; targn = gj; }
                    }
                } else {
#pragma unroll
                    for (int ct = 0; ct < 4; ++ct) {
                        const int gj = j0 + wc * 64 + ct * 16 + lanelo;
                        const float v = acc[rt][ct][r];
                        if (v > tmax) { tmax = v; targ = gj; }
                        if (v < tmin) { tmin = v; targn = gj; }
                    }
                }
#pragma unroll
                for (int msk = 1; msk < 16; msk <<= 1) {
                    const float v2 = __shfl_xor(tmax, msk, 64);
                    const int i2 = __shfl_xor(targ, msk, 64);
                    if (v2 > tmax) { tmax = v2; targ = i2; }
                    const float v3 = __shfl_xor(tmin, msk, 64);
                    const int i3 = __shfl_xor(targn, msk, 64);
                    if (v3 < tmin) { tmin = v3; targn = i3; }
                }
                if (lanelo == 0) {
                    const int o = wc * 128 + lrow;
                    rm[o] = tmax; rmn[o] = tmin;
                    ra[o] = targ; ran[o] = targn;
                }
            }
        }

        // ---- phase 2: col max/min (strict-upper only, original acc) ----
        if (!isdiag) {
#pragma unroll
            for (int ct = 0; ct < 4; ++ct) {
                const int lcol = wc * 64 + ct * 16 + lanelo;
                float tmax = NEGF; int targ = 0;
                float tmin = POSF; int targn = 0;
#pragma unroll
                for (int rt = 0; rt < 4; ++rt)
#pragma unroll
                    for (int r = 0; r < 4; ++r) {
                        const int gi = i0 + wr * 64 + rt * 16 + quad * 4 + r;
                        const float v = acc[rt][ct][r];
                        if (v > tmax) { tmax = v; targ = gi; }  // gi asc in (rt,r)
                        if (v < tmin) { tmin = v; targn = gi; }
                    }
#pragma unroll
                for (int msk = 16; msk < 64; msk <<= 1) {
                    const float m2 = __shfl_xor(tmax, msk, 64);
                    const int i2 = __shfl_xor(targ, msk, 64);
                    if (m2 > tmax) { tmax = m2; targ = i2; }
                    const float mn2 = __shfl_xor(tmin, msk, 64);
                    const int in2 = __shfl_xor(targn, msk, 64);
                    if (mn2 < tmin) { tmin = mn2; targn = in2; }
                }
                if (quad == 0) {
                    const int o = wr * 128 + lcol;
                    cm[o] = tmax; cmn[o] = tmin;
                    ca[o] = targ; can[o] = targn;
                }
            }
        }

        // ---- phase 3: acc <- exp(S-1); then zero the 16 diag entries ----
#pragma unroll
        for (int rt = 0; rt < 4; ++rt)
#pragma unroll
            for (int ct = 0; ct < 4; ++ct)
#pragma unroll
                for (int r = 0; r < 4; ++r)
                    acc[rt][ct][r] = __expf(acc[rt][ct][r] - 1.f);
        if (isdiag && wr == wc) {
#pragma unroll
            for (int rt = 0; rt < 4; ++rt)
#pragma unroll
                for (int r = 0; r < 4; ++r)
                    if (lanelo == quad * 4 + r) acc[rt][rt][r] = 0.f;
        }

        // ---- phase 4: row Zref sums ----
#pragma unroll
        for (int rt = 0; rt < 4; ++rt)
#pragma unroll
            for (int r = 0; r < 4; ++r) {
                float s = acc[rt][0][r] + acc[rt][1][r] +
                          acc[rt][2][r] + acc[rt][3][r];
#pragma unroll
                for (int msk = 1; msk < 16; msk <<= 1) s += __shfl_xor(s, msk, 64);
                if (lanelo == 0)
                    rz[wc * 128 + wr * 64 + rt * 16 + quad * 4 + r] = s;
            }

        // ---- phase 5: col Zref sums (strict-upper only) ----
        if (!isdiag) {
#pragma unroll
            for (int ct = 0; ct < 4; ++ct) {
                float s = 0.f;
#pragma unroll
                for (int rt = 0; rt < 4; ++rt)
                    s += acc[rt][ct][0] + acc[rt][ct][1] +
                         acc[rt][ct][2] + acc[rt][ct][3];
#pragma unroll
                for (int msk = 16; msk < 64; msk <<= 1) s += __shfl_xor(s, msk, 64);
                if (quad == 0)
                    cz[wr * 128 + wc * 64 + ct * 16 + lanelo] = s;
            }
        }

        __syncthreads();

        if (t < BM) {
            // merge row-stat wc-halves (wc0 cols < wc1): row i0+t, slot Je
            const float m0 = rm[t], m1 = rm[128 + t];
            float vmax = m0; int imax = ra[t];
            if (m1 > vmax) { vmax = m1; imax = ra[128 + t]; }
            float vmin = rmn[t]; int imin = ran[t];
            if (rmn[128 + t] < vmin) { vmin = rmn[128 + t]; imin = ran[128 + t]; }
            const size_t o = (size_t)Je * CDIM + i0 + t;
            pmax[o] = vmax; pmin[o] = vmin; pZ[o] = rz[t] + rz[128 + t];
            pamax[o] = imax; pamin[o] = imin;
        } else if (!isdiag) {
            // merge col-stat wr-halves (wr0 rows < wr1): row j0+tt, slot Ie
            const int tt = t - BM;
            const float m0 = cm[tt], m1 = cm[128 + tt];
            float vmax = m0; int imax = ca[tt];
            if (m1 > vmax) { vmax = m1; imax = ca[128 + tt]; }
            float vmin = cmn[tt]; int imin = can[tt];
            if (cmn[128 + tt] < vmin) { vmin = cmn[128 + tt]; imin = can[128 + tt]; }
            const size_t o = (size_t)Ie * CDIM + j0 + tt;
            pmax[o] = vmax; pmin[o] = vmin; pZ[o] = cz[tt] + cz[128 + tt];
            pamax[o] = imax; pamin[o] = imin;
        }
        // next tile's K-loop leading __syncthreads guards these LDS reads
    }
}

// ---- k_merge: one thread per row, coalesced slot-major sweep ----
// 32 blocks x 256 threads; thread owns row = bid*256+t; loop s=0..63 reads
// pX[s*CDIM+row]: the block's 256 threads hit 256 consecutive addresses per
// array per iteration (fully coalesced; was a 32KB-stride lane gather).
// Ascending s = ascending column blocks: strict > keeps first occurrence.
__global__ __launch_bounds__(256) void k_merge(
    const float* __restrict__ pmax, const float* __restrict__ pmin,
    const float* __restrict__ pZ, const int* __restrict__ pamax,
    const int* __restrict__ pamin, float* __restrict__ margin,
    int* __restrict__ ms, int* __restrict__ ls) {
    const int row = blockIdx.x * 256 + threadIdx.x;
    float M = NEGF; int a = 0;
    float mn = POSF; int b = 0;
    float Z = 0.f;
    for (int s = 0; s < NSLOT; ++s) {
        const size_t o = (size_t)s * CDIM + row;
        const float v = pmax[o];
        const int ia = pamax[o];
        const float u = pmin[o];
        const int ib = pamin[o];
        Z += pZ[o];
        if (v > M) { M = v; a = ia; }
        if (u < mn) { mn = u; b = ib; }
    }
    // P[ms]-P[ls] = (1 - exp(mn-M)) * exp(M-1) / Zref
    margin[row] = (1.f - __expf(mn - M)) * __expf(M - 1.f) / Z;
    ms[row] = a;
    ls[row] = b;
}

// ---- k_dist: per-row triplet distances, one wave per row ----
__global__ __launch_bounds__(256) void k_dist(
    const float* __restrict__ w, const float* __restrict__ margin,
    const int* __restrict__ ms, const int* __restrict__ ls,
    float* __restrict__ vals) {
    const int wave = threadIdx.x >> 6;
    const int lane = threadIdx.x & 63;
    const int row = blockIdx.x * 4 + wave;
    const int jm = ms[row], jl = ls[row];
    const float4* wi = (const float4*)(w + (size_t)row * DDIM);
    const float4* wm = (const float4*)(w + (size_t)jm * DDIM);
    const float4* wl = (const float4*)(w + (size_t)jl * DDIM);
    float sm = 0.f, sl = 0.f;
#pragma unroll
    for (int h = 0; h < 2; ++h) {
        const int idx = h * 64 + lane;
        const float4 x = wi[idx];
        const float4 y = wm[idx];
        const float4 c = wl[idx];
        float d;
        d = x.x - y.x; sm = fmaf(d, d, sm);
        d = x.y - y.y; sm = fmaf(d, d, sm);
        d = x.z - y.z; sm = fmaf(d, d, sm);
        d = x.w - y.w; sm = fmaf(d, d, sm);
        d = x.x - c.x; sl = fmaf(d, d, sl);
        d = x.y - c.y; sl = fmaf(d, d, sl);
        d = x.z - c.z; sl = fmaf(d, d, sl);
        d = x.w - c.w; sl = fmaf(d, d, sl);
    }
#pragma unroll
    for (int msk = 1; msk < 64; msk <<= 1) {
        sm += __shfl_xor(sm, msk, 64);
        sl += __shfl_xor(sl, msk, 64);
    }
    if (lane == 0) {
        const float val = sqrtf(sm) - sqrtf(sl) + margin[row];
        vals[row] = val > 0.f ? val : 0.f;
    }
}

// ---- k_final: deterministic fixed-order mean (no atomics) ----
__global__ __launch_bounds__(256) void k_final(const float* __restrict__ vals,
                                               float* __restrict__ out) {
    __shared__ float red[256];
    float s = 0.f;
    for (int i = threadIdx.x; i < CDIM; i += 256) s += vals[i];
    red[threadIdx.x] = s;
    __syncthreads();
#pragma unroll
    for (int k = 128; k > 0; k >>= 1) {
        if (threadIdx.x < (unsigned)k) red[threadIdx.x] += red[threadIdx.x + k];
        __syncthreads();
    }
    if (threadIdx.x == 0) out[0] = red[0] * (1.0f / CDIM);
}

extern "C" void kernel_launch(void* const* d_in, const int* in_sizes, int n_in,
                              void* d_out, int out_size, void* d_ws, size_t ws_size,
                              hipStream_t stream) {
    const float* g = (const float*)d_in[0];  // gt_class_embeddings [8192,512]
    const float* w = (const float*)d_in[1];  // w [8192,512]
    float* out = (float*)d_out;

    // workspace layout (~26.6 MB)
    unsigned short* ghi = (unsigned short*)d_ws;
    unsigned short* glo = ghi + (size_t)CDIM * DDIM;
    float* p = (float*)(glo + (size_t)CDIM * DDIM);
    float* pmax = p;      p += (size_t)NSLOT * CDIM;
    float* pmin = p;      p += (size_t)NSLOT * CDIM;
    float* pZ = p;        p += (size_t)NSLOT * CDIM;
    int* pamax = (int*)p; p += (size_t)NSLOT * CDIM;
    int* pamin = (int*)p; p += (size_t)NSLOT * CDIM;
    float* vals = p;      p += CDIM;
    float* margin = p;    p += CDIM;
    int* ms = (int*)p;    p += CDIM;
    int* ls = (int*)p;    p += CDIM;

    k_prep<<<CDIM / 4, 256, 0, stream>>>(g, ghi, glo);
    k_simstats<<<2048, 256, 0, stream>>>(ghi, glo, pmax, pmin, pZ, pamax, pamin);
    k_merge<<<CDIM / 256, 256, 0, stream>>>(pmax, pmin, pZ, pamax, pamin,
                                            margin, ms, ls);
    k_dist<<<CDIM / 4, 256, 0, stream>>>(w, margin, ms, ls, vals);
    k_final<<<1, 256, 0, stream>>>(vals, out);
}

// Round 11
// 244.698 us; speedup vs baseline: 1.4535x; 1.0210x over previous
//
#include <hip/hip_runtime.h>
#include <math.h>

#define CDIM 8192
#define DDIM 512
#define NEGF -3.0e38f
#define POSF  3.0e38f

#define BM 128
#define NSLOT (CDIM / BM) /* 64 col-slots of 128 per row */

typedef __attribute__((ext_vector_type(8))) short bf16x8;
typedef __attribute__((ext_vector_type(4))) float f32x4;

__device__ __forceinline__ unsigned short f2bf(float x) {
    unsigned int u = __float_as_uint(x);
    u += 0x7fffu + ((u >> 16) & 1u);
    return (unsigned short)(u >> 16);
}
__device__ __forceinline__ float bf2f(unsigned short h) {
    return __uint_as_float(((unsigned int)h) << 16);
}
// async global->LDS, 16B per lane. LDS dest is wave-uniform base + lane*16.
__device__ __forceinline__ void gld16(const void* g, void* l) {
    __builtin_amdgcn_global_load_lds(
        (__attribute__((address_space(1))) void*)(void*)g,
        (__attribute__((address_space(3))) void*)l, 16, 0, 0);
}

// ---- k_prep: normalize rows of G, split into bf16 hi/lo ----
__global__ __launch_bounds__(256) void k_prep(const float* __restrict__ g,
                                              unsigned short* __restrict__ hi,
                                              unsigned short* __restrict__ lo) {
    const int wave = threadIdx.x >> 6;
    const int lane = threadIdx.x & 63;
    const int row = blockIdx.x * 4 + wave;
    const float4* src = (const float4*)(g + (size_t)row * DDIM);
    const float4 a = src[lane * 2];
    const float4 b = src[lane * 2 + 1];
    float s = a.x * a.x + a.y * a.y + a.z * a.z + a.w * a.w +
              b.x * b.x + b.y * b.y + b.z * b.z + b.w * b.w;
#pragma unroll
    for (int m = 1; m < 64; m <<= 1) s += __shfl_xor(s, m, 64);
    const float rn = rsqrtf(s);
    const float y[8] = {a.x * rn, a.y * rn, a.z * rn, a.w * rn,
                        b.x * rn, b.y * rn, b.z * rn, b.w * rn};
    unsigned int hv[4], lv[4];
#pragma unroll
    for (int i = 0; i < 4; ++i) {
        const unsigned short h0 = f2bf(y[2 * i]);
        const unsigned short h1 = f2bf(y[2 * i + 1]);
        const unsigned short l0 = f2bf(y[2 * i] - bf2f(h0));
        const unsigned short l1 = f2bf(y[2 * i + 1] - bf2f(h1));
        hv[i] = (unsigned int)h0 | ((unsigned int)h1 << 16);
        lv[i] = (unsigned int)l0 | ((unsigned int)l1 << 16);
    }
    uint4* dh = (uint4*)(hi + (size_t)row * DDIM + lane * 8);
    uint4* dl = (uint4*)(lo + (size_t)row * DDIM + lane * 8);
    *dh = make_uint4(hv[0], hv[1], hv[2], hv[3]);
    *dl = make_uint4(lv[0], lv[1], lv[2], lv[3]);
}

// Off-diag super-tile assignment table: code = SI*8+SJ (SI<SJ, 8x8 super
// grid over the 64x64 tile grid). XCD0-3: 3 supers each (idx xcd*3+sup);
// XCD4-7: 4 supers each (idx 12+(xcd-4)*4+sup). Greedy-balanced:
// XCD0-3 also carry 2 diagonal supers (36 tiles) -> 264 tiles; XCD4-7: 256.
__device__ __constant__ unsigned char OSUP[28] = {
    1, 2, 10,   3, 11, 19,   4, 12, 20,   28, 5, 13,
    21, 29, 37, 6,   14, 22, 30, 38,   46, 7, 15, 23,   31, 39, 47, 55};

// ---- k_simstats: symmetric, L2 super-tiled, co-staged, BK=32, 32KB LDS ----
// Fixed-reference softmax: Zref = sum exp(S-1) (S in [-1,1] -> exp in
// [.135,1]: no overflow/underflow, partials add plainly).
// 2112 blocks; bid%8 = XCD. Each XCD owns whole 8x8 super-tiles of the tile
// grid; within a super, I varies fastest (8 consecutive blocks share the
// B-tile; the super's A-band+B-band [4 MB hi+lo] stays L2-resident for all
// 64 tiles -> ~4x less L2-miss traffic than J-major streaming).
// 128x128 tile, 4 waves 2x2, rt4 x ct4 16x16x32 frags; per K-chunk (BK=32)
// stage Ahi|Alo|Bhi|Blo (32 KB) and run hi*hi+hi*lo+lo*hi.
// Strict-upper tiles also emit col stats (mirror rows, S=S^T). Slot p of row
// i covers cols [p*128,(p+1)*128): row-stats->slot J, col-stats->slot I.
// Cross-lane merges use strict >/< without index tie-break (exact fp32 value
// ties across lanes: measure-zero; in-lane scan order preserves numpy
// first-occurrence).
__global__ __launch_bounds__(256, 3) void k_simstats(
    const unsigned short* __restrict__ ghi, const unsigned short* __restrict__ glo,
    float* __restrict__ pmax, float* __restrict__ pmin, float* __restrict__ pZ,
    int* __restrict__ pamax, int* __restrict__ pamin) {
    // ---- tile mapping (block-uniform) ----
    const int bid = blockIdx.x;
    const int xcd = bid & 7;
    const int off = bid >> 3;
    int I, J;
    if (xcd < 4) {
        if (off < 72) {  // two diagonal supers: s = xcd*2 + (off>=36)
            const int s = xcd * 2 + (off >= 36);
            const int u = (off >= 36) ? off - 36 : off;
            int jj = 0;  // triangular: i<=j within the 8x8 super, i fastest
            while ((jj + 1) * (jj + 2) / 2 <= u) ++jj;
            const int ii = u - jj * (jj + 1) / 2;
            I = s * 8 + ii; J = s * 8 + jj;
        } else {
            const int sup = (off - 72) >> 6;
            const int u = (off - 72) & 63;
            const int code = OSUP[xcd * 3 + sup];
            I = (code >> 3) * 8 + (u & 7);   // I fastest: B-tile shared x8
            J = (code & 7) * 8 + (u >> 3);
        }
    } else {
        if (off >= 256) return;  // 32 pad blocks
        const int sup = off >> 6;
        const int u = off & 63;
        const int code = OSUP[12 + (xcd - 4) * 4 + sup];
        I = (code >> 3) * 8 + (u & 7);
        J = (code & 7) * 8 + (u >> 3);
    }

    __shared__ unsigned short SH[4 * BM * 32];  // 32 KB: Ahi|Alo|Bhi|Blo
    unsigned short* Ahi = SH;
    unsigned short* Alo = SH + 4096;
    unsigned short* Bhi = SH + 8192;
    unsigned short* Blo = SH + 12288;
    const int t = threadIdx.x;
    const int wave = t >> 6;
    const int lane = t & 63;
    const int lanelo = lane & 15;
    const int quad = lane >> 4;
    const int wr = wave & 1;
    const int wc = wave >> 1;

    // staging: per region thread t fills slots t*16 + q*4096 ->
    // (row = (t>>2)+64q, chunk-slot = t&3); src chunk = slot ^ ((row>>1)&3)
    const int srow = t >> 2;                             // 0..63
    const int scolb = ((t & 3) ^ ((t >> 3) & 3)) << 4;   // swizzled src chunk
    char* lAh = (char*)Ahi + t * 16;
    char* lAl = (char*)Alo + t * 16;
    char* lBh = (char*)Bhi + t * 16;
    char* lBl = (char*)Blo + t * 16;

    // frag-read slot (ushort units): quad ^ ((lanelo>>1)&3), loop-invariant
    const int fsl = (quad ^ ((lanelo >> 1) & 3)) << 3;
    const int aoff = (wr * 64 + lanelo) * 32 + fsl;  // + rt*16*32
    const int boff = (wc * 64 + lanelo) * 32 + fsl;  // + ct*16*32

    // epilogue LDS overlays (A half: row stats; B half: col stats)
    float* rm  = (float*)SH;            // [2 wc][128]
    float* rz  = rm + 256;
    float* rmn = rz + 256;
    int*   ra  = (int*)(rmn + 256);
    int*   ran = ra + 256;              // 5 KB < 8 KB (Ahi+Alo)
    float* cm  = (float*)Bhi;           // [2 wr][128]
    float* cz  = cm + 256;
    float* cmn = cz + 256;
    int*   ca  = (int*)(cmn + 256);
    int*   can = ca + 256;

    const int i0 = I * BM;
    const int j0 = J * BM;
    const bool isdiag = (I == J);

    f32x4 acc[4][4];
#pragma unroll
    for (int rt = 0; rt < 4; ++rt)
#pragma unroll
        for (int ct = 0; ct < 4; ++ct)
            acc[rt][ct] = (f32x4){0.f, 0.f, 0.f, 0.f};

    const char* baseAh = (const char*)ghi + (size_t)(i0 + srow) * 1024 + scolb;
    const char* baseAl = (const char*)glo + (size_t)(i0 + srow) * 1024 + scolb;
    const char* baseBh = (const char*)ghi + (size_t)(j0 + srow) * 1024 + scolb;
    const char* baseBl = (const char*)glo + (size_t)(j0 + srow) * 1024 + scolb;

    for (int k0 = 0; k0 < DDIM; k0 += 32) {
        __syncthreads();  // prior frag/epilogue LDS reads done
#pragma unroll
        for (int q = 0; q < 2; ++q) {
            const size_t roff = (size_t)q * 64 * 1024 + k0 * 2;
            gld16(baseAh + roff, lAh + q * 4096);
            gld16(baseAl + roff, lAl + q * 4096);
            gld16(baseBh + roff, lBh + q * 4096);
            gld16(baseBl + roff, lBl + q * 4096);
        }
        __syncthreads();  // drains vmcnt: staged data visible
        bf16x8 ah[4], al[4];
#pragma unroll
        for (int rt = 0; rt < 4; ++rt) {
            ah[rt] = *(const bf16x8*)&Ahi[aoff + rt * 512];
            al[rt] = *(const bf16x8*)&Alo[aoff + rt * 512];
        }
#pragma unroll
        for (int ct = 0; ct < 4; ++ct) {
            const bf16x8 bh = *(const bf16x8*)&Bhi[boff + ct * 512];
            const bf16x8 bl = *(const bf16x8*)&Blo[boff + ct * 512];
#pragma unroll
            for (int rt = 0; rt < 4; ++rt) {
                acc[rt][ct] = __builtin_amdgcn_mfma_f32_16x16x32_bf16(
                    ah[rt], bh, acc[rt][ct], 0, 0, 0);
                acc[rt][ct] = __builtin_amdgcn_mfma_f32_16x16x32_bf16(
                    ah[rt], bl, acc[rt][ct], 0, 0, 0);
                acc[rt][ct] = __builtin_amdgcn_mfma_f32_16x16x32_bf16(
                    al[rt], bh, acc[rt][ct], 0, 0, 0);
            }
        }
    }

    __syncthreads();  // all frag reads done before LDS overlay

    // ---- phase 1: row max/min (original acc) ----
    // C/D layout: col = lanelo, row = quad*4 + reg  [m89]
#pragma unroll
    for (int rt = 0; rt < 4; ++rt) {
#pragma unroll
        for (int r = 0; r < 4; ++r) {
            const int lrow = wr * 64 + rt * 16 + quad * 4 + r;
            float tmax = NEGF; int targ = 0;
            float tmin = POSF; int targn = 0;
            if (isdiag) {
                const int gi = i0 + lrow;
#pragma unroll
                for (int ct = 0; ct < 4; ++ct) {
                    const int gj = j0 + wc * 64 + ct * 16 + lanelo;
                    const float v = acc[rt][ct][r];
                    const bool dg = (gj == gi);
                    const float vM = dg ? NEGF : v;
                    const float vm = dg ? POSF : v;
                    if (vM > tmax) { tmax = vM; targ = gj; }  // ct asc = j asc
                    if (vm < tmin) { tmin = vm; targn = gj; }
                }
            } else {
#pragma unroll
                for (int ct = 0; ct < 4; ++ct) {
                    const int gj = j0 + wc * 64 + ct * 16 + lanelo;
                    const float v = acc[rt][ct][r];
                    if (v > tmax) { tmax = v; targ = gj; }
                    if (v < tmin) { tmin = v; targn = gj; }
                }
            }
#pragma unroll
            for (int msk = 1; msk < 16; msk <<= 1) {
                const float v2 = __shfl_xor(tmax, msk, 64);
                const int i2 = __shfl_xor(targ, msk, 64);
                if (v2 > tmax) { tmax = v2; targ = i2; }
                const float v3 = __shfl_xor(tmin, msk, 64);
                const int i3 = __shfl_xor(targn, msk, 64);
                if (v3 < tmin) { tmin = v3; targn = i3; }
            }
            if (lanelo == 0) {
                const int o = wc * 128 + lrow;
                rm[o] = tmax; rmn[o] = tmin;
                ra[o] = targ; ran[o] = targn;
            }
        }
    }

    // ---- phase 2: col max/min (strict-upper only, original acc) ----
    if (!isdiag) {
#pragma unroll
        for (int ct = 0; ct < 4; ++ct) {
            const int lcol = wc * 64 + ct * 16 + lanelo;
            float tmax = NEGF; int targ = 0;
            float tmin = POSF; int targn = 0;
#pragma unroll
            for (int rt = 0; rt < 4; ++rt)
#pragma unroll
                for (int r = 0; r < 4; ++r) {
                    const int gi = i0 + wr * 64 + rt * 16 + quad * 4 + r;
                    const float v = acc[rt][ct][r];
                    if (v > tmax) { tmax = v; targ = gi; }  // gi asc in (rt,r)
                    if (v < tmin) { tmin = v; targn = gi; }
                }
#pragma unroll
            for (int msk = 16; msk < 64; msk <<= 1) {
                const float m2 = __shfl_xor(tmax, msk, 64);
                const int i2 = __shfl_xor(targ, msk, 64);
                if (m2 > tmax) { tmax = m2; targ = i2; }
                const float mn2 = __shfl_xor(tmin, msk, 64);
                const int in2 = __shfl_xor(targn, msk, 64);
                if (mn2 < tmin) { tmin = mn2; targn = in2; }
            }
            if (quad == 0) {
                const int o = wr * 128 + lcol;
                cm[o] = tmax; cmn[o] = tmin;
                ca[o] = targ; can[o] = targn;
            }
        }
    }

    // ---- phase 3: acc <- exp(S-1); then zero the 16 diag entries ----
#pragma unroll
    for (int rt = 0; rt < 4; ++rt)
#pragma unroll
        for (int ct = 0; ct < 4; ++ct)
#pragma unroll
            for (int r = 0; r < 4; ++r)
                acc[rt][ct][r] = __expf(acc[rt][ct][r] - 1.f);
    if (isdiag && wr == wc) {
#pragma unroll
        for (int rt = 0; rt < 4; ++rt)
#pragma unroll
            for (int r = 0; r < 4; ++r)
                if (lanelo == quad * 4 + r) acc[rt][rt][r] = 0.f;
    }

    // ---- phase 4: row Zref sums ----
#pragma unroll
    for (int rt = 0; rt < 4; ++rt)
#pragma unroll
        for (int r = 0; r < 4; ++r) {
            float s = acc[rt][0][r] + acc[rt][1][r] +
                      acc[rt][2][r] + acc[rt][3][r];
#pragma unroll
            for (int msk = 1; msk < 16; msk <<= 1) s += __shfl_xor(s, msk, 64);
            if (lanelo == 0)
                rz[wc * 128 + wr * 64 + rt * 16 + quad * 4 + r] = s;
        }

    // ---- phase 5: col Zref sums (strict-upper only) ----
    if (!isdiag) {
#pragma unroll
        for (int ct = 0; ct < 4; ++ct) {
            float s = 0.f;
#pragma unroll
            for (int rt = 0; rt < 4; ++rt)
                s += acc[rt][ct][0] + acc[rt][ct][1] +
                     acc[rt][ct][2] + acc[rt][ct][3];
#pragma unroll
            for (int msk = 16; msk < 64; msk <<= 1) s += __shfl_xor(s, msk, 64);
            if (quad == 0)
                cz[wr * 128 + wc * 64 + ct * 16 + lanelo] = s;
        }
    }

    __syncthreads();

    if (t < BM) {
        // merge row-stat wc-halves (wc0 cols < wc1): row i0+t, slot J
        const float m0 = rm[t], m1 = rm[128 + t];
        float vmax = m0; int imax = ra[t];
        if (m1 > vmax) { vmax = m1; imax = ra[128 + t]; }
        float vmin = rmn[t]; int imin = ran[t];
        if (rmn[128 + t] < vmin) { vmin = rmn[128 + t]; imin = ran[128 + t]; }
        const size_t o = (size_t)J * CDIM + i0 + t;
        pmax[o] = vmax; pmin[o] = vmin; pZ[o] = rz[t] + rz[128 + t];
        pamax[o] = imax; pamin[o] = imin;
    } else if (!isdiag) {
        // merge col-stat wr-halves (wr0 rows < wr1): row j0+tt, slot I
        const int tt = t - BM;
        const float m0 = cm[tt], m1 = cm[128 + tt];
        float vmax = m0; int imax = ca[tt];
        if (m1 > vmax) { vmax = m1; imax = ca[128 + tt]; }
        float vmin = cmn[tt]; int imin = can[tt];
        if (cmn[128 + tt] < vmin) { vmin = cmn[128 + tt]; imin = can[128 + tt]; }
        const size_t o = (size_t)I * CDIM + j0 + tt;
        pmax[o] = vmax; pmin[o] = vmin; pZ[o] = cz[tt] + cz[128 + tt];
        pamax[o] = imax; pamin[o] = imin;
    }
}

// ---- k_merge: one thread per row, coalesced slot-major sweep ----
// Ascending s = ascending column blocks: strict > keeps first occurrence.
__global__ __launch_bounds__(256) void k_merge(
    const float* __restrict__ pmax, const float* __restrict__ pmin,
    const float* __restrict__ pZ, const int* __restrict__ pamax,
    const int* __restrict__ pamin, float* __restrict__ margin,
    int* __restrict__ ms, int* __restrict__ ls) {
    const int row = blockIdx.x * 256 + threadIdx.x;
    float M = NEGF; int a = 0;
    float mn = POSF; int b = 0;
    float Z = 0.f;
    for (int s = 0; s < NSLOT; ++s) {
        const size_t o = (size_t)s * CDIM + row;
        const float v = pmax[o];
        const int ia = pamax[o];
        const float u = pmin[o];
        const int ib = pamin[o];
        Z += pZ[o];
        if (v > M) { M = v; a = ia; }
        if (u < mn) { mn = u; b = ib; }
    }
    // P[ms]-P[ls] = (1 - exp(mn-M)) * exp(M-1) / Zref
    margin[row] = (1.f - __expf(mn - M)) * __expf(M - 1.f) / Z;
    ms[row] = a;
    ls[row] = b;
}

// ---- k_dist: per-row triplet distances, one wave per row ----
__global__ __launch_bounds__(256) void k_dist(
    const float* __restrict__ w, const float* __restrict__ margin,
    const int* __restrict__ ms, const int* __restrict__ ls,
    float* __restrict__ vals) {
    const int wave = threadIdx.x >> 6;
    const int lane = threadIdx.x & 63;
    const int row = blockIdx.x * 4 + wave;
    const int jm = ms[row], jl = ls[row];
    const float4* wi = (const float4*)(w + (size_t)row * DDIM);
    const float4* wm = (const float4*)(w + (size_t)jm * DDIM);
    const float4* wl = (const float4*)(w + (size_t)jl * DDIM);
    float sm = 0.f, sl = 0.f;
#pragma unroll
    for (int h = 0; h < 2; ++h) {
        const int idx = h * 64 + lane;
        const float4 x = wi[idx];
        const float4 y = wm[idx];
        const float4 c = wl[idx];
        float d;
        d = x.x - y.x; sm = fmaf(d, d, sm);
        d = x.y - y.y; sm = fmaf(d, d, sm);
        d = x.z - y.z; sm = fmaf(d, d, sm);
        d = x.w - y.w; sm = fmaf(d, d, sm);
        d = x.x - c.x; sl = fmaf(d, d, sl);
        d = x.y - c.y; sl = fmaf(d, d, sl);
        d = x.z - c.z; sl = fmaf(d, d, sl);
        d = x.w - c.w; sl = fmaf(d, d, sl);
    }
#pragma unroll
    for (int msk = 1; msk < 64; msk <<= 1) {
        sm += __shfl_xor(sm, msk, 64);
        sl += __shfl_xor(sl, msk, 64);
    }
    if (lane == 0) {
        const float val = sqrtf(sm) - sqrtf(sl) + margin[row];
        vals[row] = val > 0.f ? val : 0.f;
    }
}

// ---- k_final: deterministic fixed-order mean (no atomics) ----
__global__ __launch_bounds__(256) void k_final(const float* __restrict__ vals,
                                               float* __restrict__ out) {
    __shared__ float red[256];
    float s = 0.f;
    for (int i = threadIdx.x; i < CDIM; i += 256) s += vals[i];
    red[threadIdx.x] = s;
    __syncthreads();
#pragma unroll
    for (int k = 128; k > 0; k >>= 1) {
        if (threadIdx.x < (unsigned)k) red[threadIdx.x] += red[threadIdx.x + k];
        __syncthreads();
    }
    if (threadIdx.x == 0) out[0] = red[0] * (1.0f / CDIM);
}

extern "C" void kernel_launch(void* const* d_in, const int* in_sizes, int n_in,
                              void* d_out, int out_size, void* d_ws, size_t ws_size,
                              hipStream_t stream) {
    const float* g = (const float*)d_in[0];  // gt_class_embeddings [8192,512]
    const float* w = (const float*)d_in[1];  // w [8192,512]
    float* out = (float*)d_out;

    // workspace layout (~26.6 MB)
    unsigned short* ghi = (unsigned short*)d_ws;
    unsigned short* glo = ghi + (size_t)CDIM * DDIM;
    float* p = (float*)(glo + (size_t)CDIM * DDIM);
    float* pmax = p;      p += (size_t)NSLOT * CDIM;
    float* pmin = p;      p += (size_t)NSLOT * CDIM;
    float* pZ = p;        p += (size_t)NSLOT * CDIM;
    int* pamax = (int*)p; p += (size_t)NSLOT * CDIM;
    int* pamin = (int*)p; p += (size_t)NSLOT * CDIM;
    float* vals = p;      p += CDIM;
    float* margin = p;    p += CDIM;
    int* ms = (int*)p;    p += CDIM;
    int* ls = (int*)p;    p += CDIM;

    k_prep<<<CDIM / 4, 256, 0, stream>>>(g, ghi, glo);
    k_simstats<<<2112, 256, 0, stream>>>(ghi, glo, pmax, pmin, pZ, pamax, pamin);
    k_merge<<<CDIM / 256, 256, 0, stream>>>(pmax, pmin, pZ, pamax, pamin,
                                            margin, ms, ls);
    k_dist<<<CDIM / 4, 256, 0, stream>>>(w, margin, ms, ls, vals);
    k_final<<<1, 256, 0, stream>>>(vals, out);
}